// Round 1
// baseline (2811.303 us; speedup 1.0000x reference)
//
#include <hip/hip_runtime.h>
#include <math.h>

#define NN 10000
#define NE 100000
#define NGR 64
#define NT 5
#define FD 75
#define FOUT 15
#define NLAY 4

// ---------------------------------------------------------------- kernels

__global__ __launch_bounds__(256) void k_node_emb(const float* __restrict__ x,
    const float* __restrict__ w, const float* __restrict__ b, float* __restrict__ h) {
  int idx = blockIdx.x * 256 + threadIdx.x;
  if (idx >= NN * FD) return;
  int n = idx / FD, f = idx - n * FD;
  float acc = b[f];
#pragma unroll
  for (int k = 0; k < 14; ++k) acc += x[n * 14 + k] * w[k * FD + f];
  h[idx] = acc;
}

__global__ __launch_bounds__(256) void k_edge_emb(const float* __restrict__ eattr,
    const float* __restrict__ w, const float* __restrict__ b, float* __restrict__ ea) {
  int idx = blockIdx.x * 256 + threadIdx.x;
  if (idx >= NE * 50) return;
  int e = idx / 50, c = idx - e * 50;
  float acc = b[c];
#pragma unroll
  for (int k = 0; k < 4; ++k) acc += eattr[e * 4 + k] * w[k * 50 + c];
  ea[idx] = acc;
}

__global__ __launch_bounds__(256) void k_count(const int* __restrict__ dst, int* __restrict__ deg) {
  int e = blockIdx.x * 256 + threadIdx.x;
  if (e < NE) atomicAdd(&deg[dst[e]], 1);
}

__global__ __launch_bounds__(1024) void k_scan(const int* __restrict__ deg, int* __restrict__ rowptr) {
  __shared__ int buf[1024];
  __shared__ int carry;
  int tid = threadIdx.x;
  if (tid == 0) carry = 0;
  __syncthreads();
  for (int base = 0; base < NN; base += 1024) {
    int i = base + tid;
    int v = (i < NN) ? deg[i] : 0;
    buf[tid] = v;
    __syncthreads();
    for (int off = 1; off < 1024; off <<= 1) {
      int t = (tid >= off) ? buf[tid - off] : 0;
      __syncthreads();
      buf[tid] += t;
      __syncthreads();
    }
    int inc = buf[tid];
    int tot = buf[1023];
    if (i < NN) rowptr[i + 1] = carry + inc;
    __syncthreads();
    if (tid == 0) carry += tot;
    __syncthreads();
  }
  if (tid == 0) rowptr[0] = 0;
}

__global__ __launch_bounds__(256) void k_scl(const int* __restrict__ deg, float* __restrict__ scl,
                                             float* __restrict__ iscl, float inv_avg_log) {
  int n = blockIdx.x * 256 + threadIdx.x;
  if (n >= NN) return;
  float c1 = fmaxf((float)deg[n], 1.f);
  float s = logf(c1 + 1.f) * inv_avg_log;
  scl[n] = s;
  iscl[n] = 1.f / s;
}

__global__ __launch_bounds__(256) void k_scatter(const int* __restrict__ dst, const int* __restrict__ rowptr,
    int* __restrict__ cursor, int* __restrict__ eids) {
  int e = blockIdx.x * 256 + threadIdx.x;
  if (e >= NE) return;
  int d = dst[e];
  int pos = rowptr[d] + atomicAdd(&cursor[d], 1);
  eids[pos] = e;
}

// Build combined pre-weights: Wc[k][t*75+g], k in [0,200): rows 0..149 = pre_w for
// [x_dst | x_src]; rows 150..199 = ee_w @ pre_w[150:225]  (edge-encoder folded in).
__global__ __launch_bounds__(256) void k_combine(const float* __restrict__ pre_w, const float* __restrict__ pre_b,
    const float* __restrict__ ee_w, const float* __restrict__ ee_b,
    float* __restrict__ Wc, float* __restrict__ bc) {
  int idx = blockIdx.x * 256 + threadIdx.x;
  if (idx >= 200 * 375) return;
  int k = idx / 375, c = idx - k * 375;
  int t = c / FD, g = c - t * FD;
  float v;
  if (k < 150) {
    v = pre_w[(t * 225 + k) * FD + g];
  } else {
    int kk = k - 150;
    float a = 0.f;
    for (int f2 = 0; f2 < FD; ++f2) a += ee_w[kk * FD + f2] * pre_w[(t * 225 + 150 + f2) * FD + g];
    v = a;
  }
  Wc[k * 375 + c] = v;
  if (k == 0) {
    float a = pre_b[t * FD + g];
    for (int f2 = 0; f2 < FD; ++f2) a += ee_b[f2] * pre_w[(t * 225 + 150 + f2) * FD + g];
    bc[c] = a;
  }
}

// m[r][t*75+g] for CSR row r (edge eids[r]):  [h[dst] | h[src] | ea[e]] (K=200) @ Wc + bc
// grid (ceil(E/64), 5 towers), block 256 = 16x16; thread tile 4 rows x 5 cols.
__global__ __launch_bounds__(256) void k_pre(const float* __restrict__ h, const float* __restrict__ ea,
    const int* __restrict__ eids, const int* __restrict__ srcA, const int* __restrict__ dstA,
    const float* __restrict__ Wc, const float* __restrict__ bc, float* __restrict__ m) {
  __shared__ float As[25][64];
  __shared__ float Bs[25][80];
  __shared__ int rowD[64], rowS[64], rowE[64];
  const int t = blockIdx.y;
  const int rowBase = blockIdx.x * 64;
  const int tid = threadIdx.x;
  if (tid < 64) {
    int R = rowBase + tid;
    int e = (R < NE) ? eids[R] : 0;
    rowE[tid] = e * 50;
    rowS[tid] = srcA[e] * FD;
    rowD[tid] = (R < NE) ? dstA[e] * FD : -1;
  }
  __syncthreads();
  const int ty = tid >> 4, tx = tid & 15;
  float acc[4][5];
#pragma unroll
  for (int i = 0; i < 4; ++i)
#pragma unroll
    for (int j = 0; j < 5; ++j) acc[i][j] = 0.f;

  for (int c = 0; c < 8; ++c) {
    for (int idx = tid; idx < 1600; idx += 256) {
      int kk = idx >> 6, rr = idx & 63;
      float v = 0.f;
      int d = rowD[rr];
      if (d >= 0) {
        if (c < 3)      v = h[d + c * 25 + kk];
        else if (c < 6) v = h[rowS[rr] + (c - 3) * 25 + kk];
        else            v = ea[rowE[rr] + (c - 6) * 25 + kk];
      }
      As[kk][rr] = v;
    }
    for (int idx = tid; idx < 2000; idx += 256) {
      int kk = idx / 80, cc = idx - kk * 80;
      Bs[kk][cc] = (cc < 75) ? Wc[(c * 25 + kk) * 375 + t * 75 + cc] : 0.f;
    }
    __syncthreads();
#pragma unroll
    for (int kk = 0; kk < 25; ++kk) {
      float4 a = *reinterpret_cast<const float4*>(&As[kk][ty * 4]);
      float b0 = Bs[kk][tx], b1 = Bs[kk][tx + 16], b2 = Bs[kk][tx + 32], b3 = Bs[kk][tx + 48], b4 = Bs[kk][tx + 64];
      acc[0][0] += a.x * b0; acc[0][1] += a.x * b1; acc[0][2] += a.x * b2; acc[0][3] += a.x * b3; acc[0][4] += a.x * b4;
      acc[1][0] += a.y * b0; acc[1][1] += a.y * b1; acc[1][2] += a.y * b2; acc[1][3] += a.y * b3; acc[1][4] += a.y * b4;
      acc[2][0] += a.z * b0; acc[2][1] += a.z * b1; acc[2][2] += a.z * b2; acc[2][3] += a.z * b3; acc[2][4] += a.z * b4;
      acc[3][0] += a.w * b0; acc[3][1] += a.w * b1; acc[3][2] += a.w * b2; acc[3][3] += a.w * b3; acc[3][4] += a.w * b4;
    }
    __syncthreads();
  }
#pragma unroll
  for (int i = 0; i < 4; ++i) {
    int R = rowBase + ty * 4 + i;
    if (R >= NE) continue;
#pragma unroll
    for (int j = 0; j < 5; ++j) {
      int col = tx + 16 * j;
      if (col < 75) m[(size_t)R * 375 + t * 75 + col] = acc[i][j] + bc[t * 75 + col];
    }
  }
}

// per-node segment mean/min/max/std over CSR range; agg[n][t][0:300] = [mean|min|max|std]
__global__ __launch_bounds__(384) void k_agg(const float* __restrict__ m, const int* __restrict__ rowptr,
                                             float* __restrict__ agg) {
  int n = blockIdx.x;
  int c = threadIdx.x;
  if (c >= 375) return;
  int r0 = rowptr[n], r1 = rowptr[n + 1];
  float s = 0.f, s2 = 0.f, mn = INFINITY, mx = -INFINITY;
  for (int r = r0; r < r1; ++r) {
    float v = m[(size_t)r * 375 + c];
    s += v; s2 += v * v;
    mn = fminf(mn, v); mx = fmaxf(mx, v);
  }
  int d = r1 - r0;
  float cnt1 = (d > 0) ? (float)d : 1.f;
  float mean = s / cnt1, msq = s2 / cnt1;
  float var = msq - mean * mean;
  if (var < 0.f) var = 0.f;
  float sd = sqrtf(var + 1e-5f);
  if (d == 0) { mn = 0.f; mx = 0.f; }
  int tt = c / FD, g = c - tt * FD;
  float* ag = agg + ((size_t)n * NT + tt) * 300;
  ag[g] = mean; ag[75 + g] = mn; ag[150 + g] = mx; ag[225 + g] = sd;
}

// y[n][t*15+o] = [x | agg | agg*scl | agg/scl] (K=975) @ post_w[t] + post_b[t]
// grid (ceil(N/64), 5); block 256: ty=node(64), tx=out-group(4x4)
__global__ __launch_bounds__(256) void k_post(const float* __restrict__ h, const float* __restrict__ agg,
    const float* __restrict__ scl, const float* __restrict__ iscl,
    const float* __restrict__ pw, const float* __restrict__ pb, float* __restrict__ y) {
  __shared__ float in_t[75][64];
  __shared__ float w_t[75][16];
  const int t = blockIdx.y;
  const int n0 = blockIdx.x * 64;
  const int tid = threadIdx.x;
  const int ty = tid >> 2, tx = tid & 3;
  float acc0 = 0.f, acc1 = 0.f, acc2 = 0.f, acc3 = 0.f;
  for (int c = 0; c < 13; ++c) {
    for (int idx = tid; idx < 4800; idx += 256) {
      int kk = idx >> 6, node = idx & 63;
      int nn = n0 + node;
      float v = 0.f;
      if (nn < NN) {
        if (c == 0) {
          v = h[(size_t)nn * FD + kk];
        } else {
          int q = c - 1;
          int seg = q >> 2;
          int jb = (q & 3) * 75 + kk;
          float a = agg[((size_t)nn * NT + t) * 300 + jb];
          v = (seg == 0) ? a : ((seg == 1) ? a * scl[nn] : a * iscl[nn]);
        }
      }
      in_t[kk][node] = v;
    }
    for (int idx = tid; idx < 1200; idx += 256) {
      int kk = idx >> 4, o = idx & 15;
      w_t[kk][o] = (o < 15) ? pw[((size_t)t * 975 + c * 75 + kk) * 15 + o] : 0.f;
    }
    __syncthreads();
#pragma unroll
    for (int kk = 0; kk < 75; ++kk) {
      float a = in_t[kk][ty];
      float4 w = *reinterpret_cast<const float4*>(&w_t[kk][tx * 4]);
      acc0 += a * w.x; acc1 += a * w.y; acc2 += a * w.z; acc3 += a * w.w;
    }
    __syncthreads();
  }
  int n = n0 + ty;
  if (n < NN) {
    float r[4] = {acc0, acc1, acc2, acc3};
#pragma unroll
    for (int j = 0; j < 4; ++j) {
      int o = tx * 4 + j;
      if (o < FOUT) y[(size_t)n * FD + t * FOUT + o] = r[j] + pb[t * FOUT + o];
    }
  }
}

__global__ __launch_bounds__(256) void k_lin(const float* __restrict__ y, const float* __restrict__ w,
    const float* __restrict__ b, float* __restrict__ z) {
  int idx = blockIdx.x * 256 + threadIdx.x;
  if (idx >= NN * FD) return;
  int n = idx / FD, f = idx - n * FD;
  float a = b[f];
  for (int j = 0; j < FD; ++j) a += y[(size_t)n * FD + j] * w[j * FD + f];
  z[idx] = a;
}

__global__ __launch_bounds__(256) void k_bnstat(const float* __restrict__ z, float* __restrict__ stat) {
  int f = blockIdx.x;
  float s = 0.f, s2 = 0.f;
  for (int n = threadIdx.x; n < NN; n += 256) {
    float v = z[(size_t)n * FD + f];
    s += v; s2 += v * v;
  }
  __shared__ float bs[256], bs2[256];
  int tid = threadIdx.x;
  bs[tid] = s; bs2[tid] = s2;
  __syncthreads();
  for (int off = 128; off > 0; off >>= 1) {
    if (tid < off) { bs[tid] += bs[tid + off]; bs2[tid] += bs2[tid + off]; }
    __syncthreads();
  }
  if (tid == 0) {
    float mu = bs[0] / (float)NN;
    float var = bs2[0] / (float)NN - mu * mu;
    var = fmaxf(var, 0.f);
    stat[f] = mu;
    stat[FD + f] = 1.f / sqrtf(var + 1e-5f);
  }
}

__global__ __launch_bounds__(256) void k_bnapply(const float* __restrict__ z, const float* __restrict__ stat,
    const float* __restrict__ g, const float* __restrict__ b, float* __restrict__ out) {
  int idx = blockIdx.x * 256 + threadIdx.x;
  if (idx >= NN * FD) return;
  int f = idx % FD;
  float v = (z[idx] - stat[f]) * stat[FD + f] * g[f] + b[f];
  out[idx] = fmaxf(v, 0.f);
}

__global__ __launch_bounds__(256) void k_pool(const float* __restrict__ h, const int* __restrict__ batch,
                                              float* __restrict__ gpool) {
  int idx = blockIdx.x * 256 + threadIdx.x;
  if (idx >= NN * FD) return;
  int n = idx / FD, f = idx - n * FD;
  atomicAdd(&gpool[batch[n] * FD + f], h[idx]);
}

__global__ __launch_bounds__(256) void k_mlp(const float* __restrict__ gpool,
    const float* __restrict__ w1, const float* __restrict__ b1,
    const float* __restrict__ w2, const float* __restrict__ b2,
    const float* __restrict__ w3, const float* __restrict__ b3,
    float* __restrict__ out) {
  __shared__ float G[NGR * FD];
  __shared__ float G1[NGR * 50];
  __shared__ float G2[NGR * 25];
  int tid = threadIdx.x;
  for (int i = tid; i < NGR * FD; i += 256) G[i] = gpool[i];
  __syncthreads();
  for (int i = tid; i < NGR * 50; i += 256) {
    int r = i / 50, c = i - r * 50;
    float a = b1[c];
    for (int k = 0; k < FD; ++k) a += G[r * FD + k] * w1[k * 50 + c];
    G1[i] = fmaxf(a, 0.f);
  }
  __syncthreads();
  for (int i = tid; i < NGR * 25; i += 256) {
    int r = i / 25, c = i - r * 25;
    float a = b2[c];
    for (int k = 0; k < 50; ++k) a += G1[r * 50 + k] * w2[k * 25 + c];
    G2[i] = fmaxf(a, 0.f);
  }
  __syncthreads();
  if (tid < NGR) {
    float a = b3[0];
    for (int k = 0; k < 25; ++k) a += G2[tid * 25 + k] * w3[k];
    out[tid] = a;
  }
}

// ---------------------------------------------------------------- host

extern "C" void kernel_launch(void* const* d_in, const int* in_sizes, int n_in,
                              void* d_out, int out_size, void* d_ws, size_t ws_size,
                              hipStream_t stream) {
  (void)in_sizes; (void)n_in; (void)out_size; (void)ws_size;
  const float* x      = (const float*)d_in[0];
  const int*   eidx   = (const int*)  d_in[1];
  const float* eattr  = (const float*)d_in[2];
  const int*   batch  = (const int*)  d_in[3];
  const float* nw     = (const float*)d_in[4];
  const float* nb     = (const float*)d_in[5];
  const float* ew     = (const float*)d_in[6];
  const float* ebias  = (const float*)d_in[7];
  const float* ee_w   = (const float*)d_in[8];
  const float* ee_b   = (const float*)d_in[9];
  const float* pre_w  = (const float*)d_in[10];
  const float* pre_b  = (const float*)d_in[11];
  const float* post_w = (const float*)d_in[12];
  const float* post_b = (const float*)d_in[13];
  const float* lin_w  = (const float*)d_in[14];
  const float* lin_b  = (const float*)d_in[15];
  const float* bn_g   = (const float*)d_in[16];
  const float* bn_b   = (const float*)d_in[17];
  const float* w1 = (const float*)d_in[18];
  const float* b1 = (const float*)d_in[19];
  const float* w2 = (const float*)d_in[20];
  const float* b2 = (const float*)d_in[21];
  const float* w3 = (const float*)d_in[22];
  const float* b3 = (const float*)d_in[23];

  const int* srcA = eidx;
  const int* dstA = eidx + NE;

  char* base = (char*)d_ws;
  size_t off = 0;
  auto alloc = [&](size_t bytes) -> char* {
    char* p = base + off;
    off = (off + bytes + 255) & ~(size_t)255;
    return p;
  };
  float* h0    = (float*)alloc((size_t)NN * FD * 4);
  float* h1    = (float*)alloc((size_t)NN * FD * 4);
  float* ea    = (float*)alloc((size_t)NE * 50 * 4);
  float* mbuf  = (float*)alloc((size_t)NE * 375 * 4);
  float* agg   = (float*)alloc((size_t)NN * NT * 300 * 4);
  float* y     = (float*)alloc((size_t)NN * FD * 4);
  float* z     = (float*)alloc((size_t)NN * FD * 4);
  float* Wc    = (float*)alloc((size_t)200 * 375 * 4);
  float* bc    = (float*)alloc(375 * 4);
  float* scl   = (float*)alloc(NN * 4);
  float* iscl  = (float*)alloc(NN * 4);
  int*   deg   = (int*)alloc(NN * 4);
  int*   rowptr= (int*)alloc((NN + 1) * 4);
  int*   cursor= (int*)alloc(NN * 4);
  int*   eids  = (int*)alloc(NE * 4);
  float* stat  = (float*)alloc(2 * FD * 4);
  float* gpool = (float*)alloc(NGR * FD * 4);

  static const int DEG_TAB[71] = {1, 72, 201, 816, 1790, 3756, 6923, 12768, 20286, 31710,
    51623, 82296, 124280, 177576, 251115, 326064, 395760, 456840, 506179, 516200, 507003,
    493746, 489256, 453936, 420025, 411320, 427761, 420700, 420500, 426780, 414284, 407008,
    394053, 360910, 322245, 313704, 282902, 270940, 237783, 209000, 193766, 177870, 162110,
    144848, 121230, 112700, 93483, 88512, 72275, 80700, 68799, 56784, 42665, 30996, 25630,
    12936, 9804, 8584, 5251, 3480, 3111, 2728, 1890, 1472, 1235, 330, 201, 68, 69, 0, 71};
  double num = 0.0, den = 0.0;
  for (int i = 0; i < 71; ++i) { num += log((double)i + 1.0) * DEG_TAB[i]; den += DEG_TAB[i]; }
  float inv_avg_log = (float)(den / num);

  hipMemsetAsync(deg, 0, NN * 4, stream);
  hipMemsetAsync(cursor, 0, NN * 4, stream);
  hipMemsetAsync(gpool, 0, NGR * FD * 4, stream);

  k_node_emb<<<(NN * FD + 255) / 256, 256, 0, stream>>>(x, nw, nb, h0);
  k_edge_emb<<<(NE * 50 + 255) / 256, 256, 0, stream>>>(eattr, ew, ebias, ea);
  k_count<<<(NE + 255) / 256, 256, 0, stream>>>(dstA, deg);
  k_scan<<<1, 1024, 0, stream>>>(deg, rowptr);
  k_scl<<<(NN + 255) / 256, 256, 0, stream>>>(deg, scl, iscl, inv_avg_log);
  k_scatter<<<(NE + 255) / 256, 256, 0, stream>>>(dstA, rowptr, cursor, eids);

  float* outp = (float*)d_out;
  float* hcur = h0;
  for (int l = 0; l < NLAY; ++l) {
    k_combine<<<(200 * 375 + 255) / 256, 256, 0, stream>>>(
        pre_w + (size_t)l * NT * 225 * FD, pre_b + (size_t)l * NT * FD,
        ee_w + (size_t)l * 50 * FD, ee_b + (size_t)l * FD, Wc, bc);
    dim3 gpre((NE + 63) / 64, NT);
    k_pre<<<gpre, 256, 0, stream>>>(hcur, ea, eids, srcA, dstA, Wc, bc, mbuf);
    k_agg<<<NN, 384, 0, stream>>>(mbuf, rowptr, agg);
    dim3 gpost((NN + 63) / 64, NT);
    k_post<<<gpost, 256, 0, stream>>>(hcur, agg, scl, iscl,
        post_w + (size_t)l * NT * 975 * FOUT, post_b + (size_t)l * NT * FOUT, y);
    k_lin<<<(NN * FD + 255) / 256, 256, 0, stream>>>(y, lin_w + (size_t)l * FD * FD,
        lin_b + (size_t)l * FD, z);
    k_bnstat<<<FD, 256, 0, stream>>>(z, stat);
    float* wdst = (l == NLAY - 1) ? (outp + NGR) : ((l % 2 == 0) ? h1 : h0);
    k_bnapply<<<(NN * FD + 255) / 256, 256, 0, stream>>>(z, stat, bn_g + (size_t)l * FD,
        bn_b + (size_t)l * FD, wdst);
    hcur = wdst;
  }

  k_pool<<<(NN * FD + 255) / 256, 256, 0, stream>>>(outp + NGR, batch, gpool);
  k_mlp<<<1, 256, 0, stream>>>(gpool, w1, b1, w2, b2, w3, b3, outp);
}

// Round 2
// 1417.725 us; speedup vs baseline: 1.9830x; 1.9830x over previous
//
#include <hip/hip_runtime.h>
#include <math.h>

#define NN 10000
#define NE 100000
#define NGR 64
#define NT 5
#define FD 75
#define FOUT 15
#define NLAY 4

typedef __bf16 bf16;
typedef __bf16 bf16x8 __attribute__((ext_vector_type(8)));
typedef float f32x4 __attribute__((ext_vector_type(4)));

// ---------------------------------------------------------------- kernels

__global__ __launch_bounds__(256) void k_node_emb(const float* __restrict__ x,
    const float* __restrict__ w, const float* __restrict__ b, float* __restrict__ h,
    bf16* __restrict__ hbf) {
  int idx = blockIdx.x * 256 + threadIdx.x;
  if (idx >= NN * FD) return;
  int n = idx / FD, f = idx - n * FD;
  float acc = b[f];
#pragma unroll
  for (int k = 0; k < 14; ++k) acc += x[n * 14 + k] * w[k * FD + f];
  h[idx] = acc;
  hbf[n * 80 + f] = (bf16)acc;
}

__global__ __launch_bounds__(256) void k_edge_emb(const float* __restrict__ eattr,
    const float* __restrict__ w, const float* __restrict__ b, bf16* __restrict__ eabf) {
  int idx = blockIdx.x * 256 + threadIdx.x;
  if (idx >= NE * 50) return;
  int e = idx / 50, c = idx - e * 50;
  float acc = b[c];
#pragma unroll
  for (int k = 0; k < 4; ++k) acc += eattr[e * 4 + k] * w[k * 50 + c];
  eabf[e * 56 + c] = (bf16)acc;
}

__global__ __launch_bounds__(256) void k_count(const int* __restrict__ dst, int* __restrict__ deg) {
  int e = blockIdx.x * 256 + threadIdx.x;
  if (e < NE) atomicAdd(&deg[dst[e]], 1);
}

__global__ __launch_bounds__(1024) void k_scan(const int* __restrict__ deg, int* __restrict__ rowptr) {
  __shared__ int buf[1024];
  __shared__ int carry;
  int tid = threadIdx.x;
  if (tid == 0) carry = 0;
  __syncthreads();
  for (int base = 0; base < NN; base += 1024) {
    int i = base + tid;
    int v = (i < NN) ? deg[i] : 0;
    buf[tid] = v;
    __syncthreads();
    for (int off = 1; off < 1024; off <<= 1) {
      int t = (tid >= off) ? buf[tid - off] : 0;
      __syncthreads();
      buf[tid] += t;
      __syncthreads();
    }
    int inc = buf[tid];
    int tot = buf[1023];
    if (i < NN) rowptr[i + 1] = carry + inc;
    __syncthreads();
    if (tid == 0) carry += tot;
    __syncthreads();
  }
  if (tid == 0) rowptr[0] = 0;
}

__global__ __launch_bounds__(256) void k_scl(const int* __restrict__ deg, float* __restrict__ scl,
                                             float* __restrict__ iscl, float inv_avg_log) {
  int n = blockIdx.x * 256 + threadIdx.x;
  if (n >= NN) return;
  float c1 = fmaxf((float)deg[n], 1.f);
  float s = logf(c1 + 1.f) * inv_avg_log;
  scl[n] = s;
  iscl[n] = 1.f / s;
}

__global__ __launch_bounds__(256) void k_scatter(const int* __restrict__ dst, const int* __restrict__ rowptr,
    int* __restrict__ cursor, int* __restrict__ eids) {
  int e = blockIdx.x * 256 + threadIdx.x;
  if (e >= NE) return;
  int d = dst[e];
  int pos = rowptr[d] + atomicAdd(&cursor[d], 1);
  eids[pos] = e;
}

// Wct[col 0..383][k_stored 0..255] bf16, pre-transposed AND pre-swizzled:
// logical K layout: [0,75) h_dst | [80,155) h_src | [160,210) folded edge-encoder | else 0.
// 16B-block swizzle within each 64-k chunk: stored_blk = logical_blk ^ (col&7).
__global__ __launch_bounds__(256) void k_combine(const float* __restrict__ pre_w,
    const float* __restrict__ pre_b, const float* __restrict__ ee_w, const float* __restrict__ ee_b,
    bf16* __restrict__ Wct, float* __restrict__ bc) {
  int idx = blockIdx.x * 256 + threadIdx.x;
  if (idx >= 384 * 256) return;
  int c = idx >> 8, s = idx & 255;
  int t = c / 75, g = c - t * 75;
  int chunk = s >> 6, within = s & 63, sblk = within >> 3, elem = within & 7;
  int lb = sblk ^ (c & 7);
  int k = chunk * 64 + lb * 8 + elem;
  float v = 0.f;
  if (c < 375) {
    if (k < 75)                    v = pre_w[(t * 225 + k) * 75 + g];
    else if (k >= 80 && k < 155)   v = pre_w[(t * 225 + 75 + (k - 80)) * 75 + g];
    else if (k >= 160 && k < 210) {
      int kk = k - 160;
      float a = 0.f;
      for (int f2 = 0; f2 < 75; ++f2) a += ee_w[kk * 75 + f2] * pre_w[(t * 225 + 150 + f2) * 75 + g];
      v = a;
    }
  }
  Wct[c * 256 + s] = (bf16)v;
  if (s == 0) {
    float a = 0.f;
    if (c < 375) {
      a = pre_b[t * 75 + g];
      for (int f2 = 0; f2 < 75; ++f2) a += ee_b[f2] * pre_w[(t * 225 + 150 + f2) * 75 + g];
    }
    bc[c] = a;
  }
}

// m[r][c] (bf16, stride 384) = A[r][0:256] @ Wct^T + bc, rows in CSR order.
// 128x128 tile, 4 waves in 2x2, each 64x64 via 4x4 mfma_f32_16x16x32_bf16.
__global__ __launch_bounds__(256) void k_pre_mfma(
    const bf16* __restrict__ hbf, const bf16* __restrict__ eabf,
    const int* __restrict__ eids, const int* __restrict__ srcA, const int* __restrict__ dstA,
    const bf16* __restrict__ Wct, const float* __restrict__ bc,
    const bf16* __restrict__ zerobuf, bf16* __restrict__ m) {
  __shared__ __align__(16) unsigned char As[16384];   // [128 rows][64 k] bf16, XOR-swizzled
  __shared__ __align__(16) unsigned char Bs[16384];   // [128 cols][64 k] bf16, XOR-swizzled
  __shared__ const bf16* pD[128];
  __shared__ const bf16* pS[128];
  __shared__ const bf16* pE[128];
  const int r0 = blockIdx.x * 128;
  const int n0 = blockIdx.y * 128;
  const int tid = threadIdx.x;
  if (tid < 128) {
    int R = r0 + tid;
    if (R < NE) {
      int e = eids[R];
      pD[tid] = hbf + dstA[e] * 80;
      pS[tid] = hbf + srcA[e] * 80;
      pE[tid] = eabf + e * 56;
    } else { pD[tid] = zerobuf; pS[tid] = zerobuf; pE[tid] = zerobuf; }
  }
  __syncthreads();
  const int lane = tid & 63;
  const int wave = tid >> 6;
  const int wr = wave >> 1, wc = wave & 1;
  const int l15 = lane & 15;
  f32x4 acc[4][4];
  f32x4 zv = {0.f, 0.f, 0.f, 0.f};
#pragma unroll
  for (int i = 0; i < 4; ++i)
#pragma unroll
    for (int j = 0; j < 4; ++j) acc[i][j] = zv;

  const int sr = tid >> 3;   // staging sub-row 0..31
  const int slb = tid & 7;   // staging block 0..7

  for (int c = 0; c < 4; ++c) {
#pragma unroll
    for (int o = 0; o < 4; ++o) {
      int r = o * 32 + sr;
      // A: gather with swizzled LDS write (logical block slb -> stored slb^(r&7))
      int g = c * 8 + slb;
      const bf16* p;
      if (g < 10)      p = pD[r] + g * 8;
      else if (g < 20) p = pS[r] + (g - 10) * 8;
      else if (g < 27) p = pE[r] + (g - 20) * 8;
      else             p = zerobuf;
      uint4 va = *(const uint4*)p;
      *(uint4*)(As + r * 128 + ((slb ^ (r & 7)) << 4)) = va;
      // B: Wct is pre-swizzled -> pure linear copy
      uint4 vb = *(const uint4*)(Wct + (n0 + r) * 256 + c * 64 + slb * 8);
      *(uint4*)(Bs + r * 128 + (slb << 4)) = vb;
    }
    __syncthreads();
#pragma unroll
    for (int kk = 0; kk < 2; ++kk) {
      int kb = kk * 4 + (lane >> 4);   // logical 16B block within chunk
      bf16x8 af[4], bfv[4];
#pragma unroll
      for (int i = 0; i < 4; ++i) {
        int row = wr * 64 + i * 16 + l15;
        af[i] = *(const bf16x8*)(As + row * 128 + ((kb ^ (row & 7)) << 4));
      }
#pragma unroll
      for (int j = 0; j < 4; ++j) {
        int col = wc * 64 + j * 16 + l15;
        bfv[j] = *(const bf16x8*)(Bs + col * 128 + ((kb ^ (col & 7)) << 4));
      }
#pragma unroll
      for (int i = 0; i < 4; ++i)
#pragma unroll
        for (int j = 0; j < 4; ++j)
          acc[i][j] = __builtin_amdgcn_mfma_f32_16x16x32_bf16(af[i], bfv[j], acc[i][j], 0, 0, 0);
    }
    __syncthreads();
  }

  const int l4 = lane >> 4;
  float bcv[4];
#pragma unroll
  for (int j = 0; j < 4; ++j) bcv[j] = bc[n0 + wc * 64 + j * 16 + l15];
#pragma unroll
  for (int i = 0; i < 4; ++i) {
    int R = r0 + wr * 64 + i * 16 + l4 * 4;
#pragma unroll
    for (int q = 0; q < 4; ++q) {
      if (R + q < NE) {
#pragma unroll
        for (int j = 0; j < 4; ++j) {
          int col = n0 + wc * 64 + j * 16 + l15;
          m[(size_t)(R + q) * 384 + col] = (bf16)(acc[i][j][q] + bcv[j]);
        }
      }
    }
  }
}

// per-node segment mean/min/max/std over CSR range (m is bf16, stride 384)
__global__ __launch_bounds__(384) void k_agg(const bf16* __restrict__ m, const int* __restrict__ rowptr,
                                             float* __restrict__ agg) {
  int n = blockIdx.x;
  int c = threadIdx.x;
  if (c >= 375) return;
  int r0 = rowptr[n], r1 = rowptr[n + 1];
  float s = 0.f, s2 = 0.f, mn = INFINITY, mx = -INFINITY;
  for (int r = r0; r < r1; ++r) {
    float v = (float)m[(size_t)r * 384 + c];
    s += v; s2 += v * v;
    mn = fminf(mn, v); mx = fmaxf(mx, v);
  }
  int d = r1 - r0;
  float cnt1 = (d > 0) ? (float)d : 1.f;
  float mean = s / cnt1, msq = s2 / cnt1;
  float var = msq - mean * mean;
  if (var < 0.f) var = 0.f;
  float sd = sqrtf(var + 1e-5f);
  if (d == 0) { mn = 0.f; mx = 0.f; }
  int tt = c / FD, g = c - tt * FD;
  float* ag = agg + ((size_t)n * NT + tt) * 300;
  ag[g] = mean; ag[75 + g] = mn; ag[150 + g] = mx; ag[225 + g] = sd;
}

// y[n][t*15+o] = [x | agg | agg*scl | agg/scl] (K=975) @ post_w[t] + post_b[t]
__global__ __launch_bounds__(256) void k_post(const float* __restrict__ h, const float* __restrict__ agg,
    const float* __restrict__ scl, const float* __restrict__ iscl,
    const float* __restrict__ pw, const float* __restrict__ pb, float* __restrict__ y) {
  __shared__ float in_t[75][64];
  __shared__ float w_t[75][16];
  const int t = blockIdx.y;
  const int n0 = blockIdx.x * 64;
  const int tid = threadIdx.x;
  const int ty = tid >> 2, tx = tid & 3;
  float acc0 = 0.f, acc1 = 0.f, acc2 = 0.f, acc3 = 0.f;
  for (int c = 0; c < 13; ++c) {
    for (int idx = tid; idx < 4800; idx += 256) {
      int kk = idx >> 6, node = idx & 63;
      int nn = n0 + node;
      float v = 0.f;
      if (nn < NN) {
        if (c == 0) {
          v = h[(size_t)nn * FD + kk];
        } else {
          int q = c - 1;
          int seg = q >> 2;
          int jb = (q & 3) * 75 + kk;
          float a = agg[((size_t)nn * NT + t) * 300 + jb];
          v = (seg == 0) ? a : ((seg == 1) ? a * scl[nn] : a * iscl[nn]);
        }
      }
      in_t[kk][node] = v;
    }
    for (int idx = tid; idx < 1200; idx += 256) {
      int kk = idx >> 4, o = idx & 15;
      w_t[kk][o] = (o < 15) ? pw[((size_t)t * 975 + c * 75 + kk) * 15 + o] : 0.f;
    }
    __syncthreads();
#pragma unroll
    for (int kk = 0; kk < 75; ++kk) {
      float a = in_t[kk][ty];
      float4 w = *reinterpret_cast<const float4*>(&w_t[kk][tx * 4]);
      acc0 += a * w.x; acc1 += a * w.y; acc2 += a * w.z; acc3 += a * w.w;
    }
    __syncthreads();
  }
  int n = n0 + ty;
  if (n < NN) {
    float r[4] = {acc0, acc1, acc2, acc3};
#pragma unroll
    for (int j = 0; j < 4; ++j) {
      int o = tx * 4 + j;
      if (o < FOUT) y[(size_t)n * FD + t * FOUT + o] = r[j] + pb[t * FOUT + o];
    }
  }
}

__global__ __launch_bounds__(256) void k_lin(const float* __restrict__ y, const float* __restrict__ w,
    const float* __restrict__ b, float* __restrict__ z) {
  int idx = blockIdx.x * 256 + threadIdx.x;
  if (idx >= NN * FD) return;
  int n = idx / FD, f = idx - n * FD;
  float a = b[f];
  for (int j = 0; j < FD; ++j) a += y[(size_t)n * FD + j] * w[j * FD + f];
  z[idx] = a;
}

__global__ __launch_bounds__(256) void k_bnstat(const float* __restrict__ z, float* __restrict__ stat) {
  int f = blockIdx.x;
  float s = 0.f, s2 = 0.f;
  for (int n = threadIdx.x; n < NN; n += 256) {
    float v = z[(size_t)n * FD + f];
    s += v; s2 += v * v;
  }
  __shared__ float bs[256], bs2[256];
  int tid = threadIdx.x;
  bs[tid] = s; bs2[tid] = s2;
  __syncthreads();
  for (int off = 128; off > 0; off >>= 1) {
    if (tid < off) { bs[tid] += bs[tid + off]; bs2[tid] += bs2[tid + off]; }
    __syncthreads();
  }
  if (tid == 0) {
    float mu = bs[0] / (float)NN;
    float var = bs2[0] / (float)NN - mu * mu;
    var = fmaxf(var, 0.f);
    stat[f] = mu;
    stat[FD + f] = 1.f / sqrtf(var + 1e-5f);
  }
}

__global__ __launch_bounds__(256) void k_bnapply(const float* __restrict__ z, const float* __restrict__ stat,
    const float* __restrict__ g, const float* __restrict__ b, float* __restrict__ out,
    bf16* __restrict__ hbf) {
  int idx = blockIdx.x * 256 + threadIdx.x;
  if (idx >= NN * FD) return;
  int n = idx / FD, f = idx - n * FD;
  float v = (z[idx] - stat[f]) * stat[FD + f] * g[f] + b[f];
  v = fmaxf(v, 0.f);
  out[idx] = v;
  hbf[n * 80 + f] = (bf16)v;
}

__global__ __launch_bounds__(256) void k_pool(const float* __restrict__ h, const int* __restrict__ batch,
                                              float* __restrict__ gpool) {
  int idx = blockIdx.x * 256 + threadIdx.x;
  if (idx >= NN * FD) return;
  int n = idx / FD, f = idx - n * FD;
  atomicAdd(&gpool[batch[n] * FD + f], h[idx]);
}

__global__ __launch_bounds__(256) void k_mlp(const float* __restrict__ gpool,
    const float* __restrict__ w1, const float* __restrict__ b1,
    const float* __restrict__ w2, const float* __restrict__ b2,
    const float* __restrict__ w3, const float* __restrict__ b3,
    float* __restrict__ out) {
  __shared__ float G[NGR * FD];
  __shared__ float G1[NGR * 50];
  __shared__ float G2[NGR * 25];
  int tid = threadIdx.x;
  for (int i = tid; i < NGR * FD; i += 256) G[i] = gpool[i];
  __syncthreads();
  for (int i = tid; i < NGR * 50; i += 256) {
    int r = i / 50, c = i - r * 50;
    float a = b1[c];
    for (int k = 0; k < FD; ++k) a += G[r * FD + k] * w1[k * 50 + c];
    G1[i] = fmaxf(a, 0.f);
  }
  __syncthreads();
  for (int i = tid; i < NGR * 25; i += 256) {
    int r = i / 25, c = i - r * 25;
    float a = b2[c];
    for (int k = 0; k < 50; ++k) a += G1[r * 50 + k] * w2[k * 25 + c];
    G2[i] = fmaxf(a, 0.f);
  }
  __syncthreads();
  if (tid < NGR) {
    float a = b3[0];
    for (int k = 0; k < 25; ++k) a += G2[tid * 25 + k] * w3[k];
    out[tid] = a;
  }
}

// ---------------------------------------------------------------- host

extern "C" void kernel_launch(void* const* d_in, const int* in_sizes, int n_in,
                              void* d_out, int out_size, void* d_ws, size_t ws_size,
                              hipStream_t stream) {
  (void)in_sizes; (void)n_in; (void)out_size; (void)ws_size;
  const float* x      = (const float*)d_in[0];
  const int*   eidx   = (const int*)  d_in[1];
  const float* eattr  = (const float*)d_in[2];
  const int*   batch  = (const int*)  d_in[3];
  const float* nw     = (const float*)d_in[4];
  const float* nb     = (const float*)d_in[5];
  const float* ew     = (const float*)d_in[6];
  const float* ebias  = (const float*)d_in[7];
  const float* ee_w   = (const float*)d_in[8];
  const float* ee_b   = (const float*)d_in[9];
  const float* pre_w  = (const float*)d_in[10];
  const float* pre_b  = (const float*)d_in[11];
  const float* post_w = (const float*)d_in[12];
  const float* post_b = (const float*)d_in[13];
  const float* lin_w  = (const float*)d_in[14];
  const float* lin_b  = (const float*)d_in[15];
  const float* bn_g   = (const float*)d_in[16];
  const float* bn_b   = (const float*)d_in[17];
  const float* w1 = (const float*)d_in[18];
  const float* b1 = (const float*)d_in[19];
  const float* w2 = (const float*)d_in[20];
  const float* b2 = (const float*)d_in[21];
  const float* w3 = (const float*)d_in[22];
  const float* b3 = (const float*)d_in[23];

  const int* srcA = eidx;
  const int* dstA = eidx + NE;

  char* base = (char*)d_ws;
  size_t off = 0;
  auto alloc = [&](size_t bytes) -> char* {
    char* p = base + off;
    off = (off + bytes + 255) & ~(size_t)255;
    return p;
  };
  float* h0    = (float*)alloc((size_t)NN * FD * 4);
  float* h1    = (float*)alloc((size_t)NN * FD * 4);
  bf16*  hbf   = (bf16*) alloc((size_t)NN * 80 * 2);
  bf16*  eabf  = (bf16*) alloc((size_t)NE * 56 * 2);
  bf16*  mbf   = (bf16*) alloc((size_t)NE * 384 * 2);
  float* agg   = (float*)alloc((size_t)NN * NT * 300 * 4);
  float* y     = (float*)alloc((size_t)NN * FD * 4);
  float* z     = (float*)alloc((size_t)NN * FD * 4);
  bf16*  Wct   = (bf16*) alloc((size_t)384 * 256 * 2);
  float* bc    = (float*)alloc(384 * 4);
  float* scl   = (float*)alloc(NN * 4);
  float* iscl  = (float*)alloc(NN * 4);
  int*   deg   = (int*)alloc(NN * 4);
  int*   rowptr= (int*)alloc((NN + 1) * 4);
  int*   cursor= (int*)alloc(NN * 4);
  int*   eids  = (int*)alloc(NE * 4);
  float* stat  = (float*)alloc(2 * FD * 4);
  float* gpool = (float*)alloc(NGR * FD * 4);
  bf16*  zerobuf = (bf16*)alloc(256);

  static const int DEG_TAB[71] = {1, 72, 201, 816, 1790, 3756, 6923, 12768, 20286, 31710,
    51623, 82296, 124280, 177576, 251115, 326064, 395760, 456840, 506179, 516200, 507003,
    493746, 489256, 453936, 420025, 411320, 427761, 420700, 420500, 426780, 414284, 407008,
    394053, 360910, 322245, 313704, 282902, 270940, 237783, 209000, 193766, 177870, 162110,
    144848, 121230, 112700, 93483, 88512, 72275, 80700, 68799, 56784, 42665, 30996, 25630,
    12936, 9804, 8584, 5251, 3480, 3111, 2728, 1890, 1472, 1235, 330, 201, 68, 69, 0, 71};
  double num = 0.0, den = 0.0;
  for (int i = 0; i < 71; ++i) { num += log((double)i + 1.0) * DEG_TAB[i]; den += DEG_TAB[i]; }
  float inv_avg_log = (float)(den / num);

  hipMemsetAsync(deg, 0, NN * 4, stream);
  hipMemsetAsync(cursor, 0, NN * 4, stream);
  hipMemsetAsync(gpool, 0, NGR * FD * 4, stream);
  hipMemsetAsync(hbf, 0, (size_t)NN * 80 * 2, stream);
  hipMemsetAsync(eabf, 0, (size_t)NE * 56 * 2, stream);
  hipMemsetAsync(zerobuf, 0, 256, stream);

  k_node_emb<<<(NN * FD + 255) / 256, 256, 0, stream>>>(x, nw, nb, h0, hbf);
  k_edge_emb<<<(NE * 50 + 255) / 256, 256, 0, stream>>>(eattr, ew, ebias, eabf);
  k_count<<<(NE + 255) / 256, 256, 0, stream>>>(dstA, deg);
  k_scan<<<1, 1024, 0, stream>>>(deg, rowptr);
  k_scl<<<(NN + 255) / 256, 256, 0, stream>>>(deg, scl, iscl, inv_avg_log);
  k_scatter<<<(NE + 255) / 256, 256, 0, stream>>>(dstA, rowptr, cursor, eids);

  float* outp = (float*)d_out;
  float* hcur = h0;
  for (int l = 0; l < NLAY; ++l) {
    k_combine<<<384, 256, 0, stream>>>(
        pre_w + (size_t)l * NT * 225 * FD, pre_b + (size_t)l * NT * FD,
        ee_w + (size_t)l * 50 * FD, ee_b + (size_t)l * FD, Wct, bc);
    dim3 gpre((NE + 127) / 128, 3);
    k_pre_mfma<<<gpre, 256, 0, stream>>>(hbf, eabf, eids, srcA, dstA, Wct, bc, zerobuf, mbf);
    k_agg<<<NN, 384, 0, stream>>>(mbf, rowptr, agg);
    dim3 gpost((NN + 63) / 64, NT);
    k_post<<<gpost, 256, 0, stream>>>(hcur, agg, scl, iscl,
        post_w + (size_t)l * NT * 975 * FOUT, post_b + (size_t)l * NT * FOUT, y);
    k_lin<<<(NN * FD + 255) / 256, 256, 0, stream>>>(y, lin_w + (size_t)l * FD * FD,
        lin_b + (size_t)l * FD, z);
    k_bnstat<<<FD, 256, 0, stream>>>(z, stat);
    float* wdst = (l == NLAY - 1) ? (outp + NGR) : ((l % 2 == 0) ? h1 : h0);
    k_bnapply<<<(NN * FD + 255) / 256, 256, 0, stream>>>(z, stat, bn_g + (size_t)l * FD,
        bn_b + (size_t)l * FD, wdst, hbf);
    hcur = wdst;
  }

  k_pool<<<(NN * FD + 255) / 256, 256, 0, stream>>>(outp + NGR, batch, gpool);
  k_mlp<<<1, 256, 0, stream>>>(gpool, w1, b1, w2, b2, w3, b3, outp);
}

// Round 3
// 1033.923 us; speedup vs baseline: 2.7191x; 1.3712x over previous
//
#include <hip/hip_runtime.h>
#include <math.h>

#define NN 10000
#define NE 100000
#define NGR 64
#define NT 5
#define FD 75
#define FOUT 15
#define NLAY 4

typedef __bf16 bf16;
typedef __bf16 bf16x8 __attribute__((ext_vector_type(8)));
typedef float f32x4 __attribute__((ext_vector_type(4)));

// ---------------------------------------------------------------- kernels

__global__ __launch_bounds__(256) void k_node_emb(const float* __restrict__ x,
    const float* __restrict__ w, const float* __restrict__ b, bf16* __restrict__ hbf) {
  int idx = blockIdx.x * 256 + threadIdx.x;
  if (idx >= NN * FD) return;
  int n = idx / FD, f = idx - n * FD;
  float acc = b[f];
#pragma unroll
  for (int k = 0; k < 14; ++k) acc += x[n * 14 + k] * w[k * FD + f];
  hbf[n * 80 + f] = (bf16)acc;
}

__global__ __launch_bounds__(256) void k_edge_emb(const float* __restrict__ eattr,
    const float* __restrict__ w, const float* __restrict__ b, bf16* __restrict__ eabf) {
  int idx = blockIdx.x * 256 + threadIdx.x;
  if (idx >= NE * 50) return;
  int e = idx / 50, c = idx - e * 50;
  float acc = b[c];
#pragma unroll
  for (int k = 0; k < 4; ++k) acc += eattr[e * 4 + k] * w[k * 50 + c];
  eabf[e * 56 + c] = (bf16)acc;
}

__global__ __launch_bounds__(256) void k_count(const int* __restrict__ dst, int* __restrict__ deg) {
  int e = blockIdx.x * 256 + threadIdx.x;
  if (e < NE) atomicAdd(&deg[dst[e]], 1);
}

__global__ __launch_bounds__(1024) void k_scan(const int* __restrict__ deg, int* __restrict__ rowptr) {
  __shared__ int buf[1024];
  __shared__ int carry;
  int tid = threadIdx.x;
  if (tid == 0) carry = 0;
  __syncthreads();
  for (int base = 0; base < NN; base += 1024) {
    int i = base + tid;
    int v = (i < NN) ? deg[i] : 0;
    buf[tid] = v;
    __syncthreads();
    for (int off = 1; off < 1024; off <<= 1) {
      int t = (tid >= off) ? buf[tid - off] : 0;
      __syncthreads();
      buf[tid] += t;
      __syncthreads();
    }
    int inc = buf[tid];
    int tot = buf[1023];
    if (i < NN) rowptr[i + 1] = carry + inc;
    __syncthreads();
    if (tid == 0) carry += tot;
    __syncthreads();
  }
  if (tid == 0) rowptr[0] = 0;
}

__global__ __launch_bounds__(256) void k_scl(const int* __restrict__ deg, float* __restrict__ scl,
                                             float* __restrict__ iscl, float inv_avg_log) {
  int n = blockIdx.x * 256 + threadIdx.x;
  if (n >= NN) return;
  float c1 = fmaxf((float)deg[n], 1.f);
  float s = logf(c1 + 1.f) * inv_avg_log;
  scl[n] = s;
  iscl[n] = 1.f / s;
}

__global__ __launch_bounds__(256) void k_scatter(const int* __restrict__ dst, const int* __restrict__ rowptr,
    int* __restrict__ cursor, int* __restrict__ eids) {
  int e = blockIdx.x * 256 + threadIdx.x;
  if (e >= NE) return;
  int d = dst[e];
  int pos = rowptr[d] + atomicAdd(&cursor[d], 1);
  eids[pos] = e;
}

// Wct[col 0..383][k_stored 0..255] bf16, pre-transposed AND pre-swizzled:
// logical K layout: [0,75) h_dst | [80,155) h_src | [160,210) folded edge-encoder | else 0.
__global__ __launch_bounds__(256) void k_combine(const float* __restrict__ pre_w,
    const float* __restrict__ pre_b, const float* __restrict__ ee_w, const float* __restrict__ ee_b,
    bf16* __restrict__ Wct, float* __restrict__ bc) {
  int idx = blockIdx.x * 256 + threadIdx.x;
  if (idx >= 384 * 256) return;
  int c = idx >> 8, s = idx & 255;
  int t = c / 75, g = c - t * 75;
  int chunk = s >> 6, within = s & 63, sblk = within >> 3, elem = within & 7;
  int lb = sblk ^ (c & 7);
  int k = chunk * 64 + lb * 8 + elem;
  float v = 0.f;
  if (c < 375) {
    if (k < 75)                    v = pre_w[(t * 225 + k) * 75 + g];
    else if (k >= 80 && k < 155)   v = pre_w[(t * 225 + 75 + (k - 80)) * 75 + g];
    else if (k >= 160 && k < 210) {
      int kk = k - 160;
      float a = 0.f;
      for (int f2 = 0; f2 < 75; ++f2) a += ee_w[kk * 75 + f2] * pre_w[(t * 225 + 150 + f2) * 75 + g];
      v = a;
    }
  }
  Wct[c * 256 + s] = (bf16)v;
  if (s == 0) {
    float a = 0.f;
    if (c < 375) {
      a = pre_b[t * 75 + g];
      for (int f2 = 0; f2 < 75; ++f2) a += ee_b[f2] * pre_w[(t * 225 + 150 + f2) * 75 + g];
    }
    bc[c] = a;
  }
}

// m[r][c] (bf16, stride 384) = A[r][0:256] @ Wct^T + bc, rows in CSR order.
__global__ __launch_bounds__(256) void k_pre_mfma(
    const bf16* __restrict__ hbf, const bf16* __restrict__ eabf,
    const int* __restrict__ eids, const int* __restrict__ srcA, const int* __restrict__ dstA,
    const bf16* __restrict__ Wct, const float* __restrict__ bc,
    const bf16* __restrict__ zerobuf, bf16* __restrict__ m) {
  __shared__ __align__(16) unsigned char As[16384];
  __shared__ __align__(16) unsigned char Bs[16384];
  __shared__ const bf16* pD[128];
  __shared__ const bf16* pS[128];
  __shared__ const bf16* pE[128];
  const int r0 = blockIdx.x * 128;
  const int n0 = blockIdx.y * 128;
  const int tid = threadIdx.x;
  if (tid < 128) {
    int R = r0 + tid;
    if (R < NE) {
      int e = eids[R];
      pD[tid] = hbf + dstA[e] * 80;
      pS[tid] = hbf + srcA[e] * 80;
      pE[tid] = eabf + e * 56;
    } else { pD[tid] = zerobuf; pS[tid] = zerobuf; pE[tid] = zerobuf; }
  }
  __syncthreads();
  const int lane = tid & 63;
  const int wave = tid >> 6;
  const int wr = wave >> 1, wc = wave & 1;
  const int l15 = lane & 15;
  f32x4 acc[4][4];
  f32x4 zv = {0.f, 0.f, 0.f, 0.f};
#pragma unroll
  for (int i = 0; i < 4; ++i)
#pragma unroll
    for (int j = 0; j < 4; ++j) acc[i][j] = zv;

  const int sr = tid >> 3;
  const int slb = tid & 7;

  for (int c = 0; c < 4; ++c) {
#pragma unroll
    for (int o = 0; o < 4; ++o) {
      int r = o * 32 + sr;
      int g = c * 8 + slb;
      const bf16* p;
      if (g < 10)      p = pD[r] + g * 8;
      else if (g < 20) p = pS[r] + (g - 10) * 8;
      else if (g < 27) p = pE[r] + (g - 20) * 8;
      else             p = zerobuf;
      uint4 va = *(const uint4*)p;
      *(uint4*)(As + r * 128 + ((slb ^ (r & 7)) << 4)) = va;
      uint4 vb = *(const uint4*)(Wct + (n0 + r) * 256 + c * 64 + slb * 8);
      *(uint4*)(Bs + r * 128 + (slb << 4)) = vb;
    }
    __syncthreads();
#pragma unroll
    for (int kk = 0; kk < 2; ++kk) {
      int kb = kk * 4 + (lane >> 4);
      bf16x8 af[4], bfv[4];
#pragma unroll
      for (int i = 0; i < 4; ++i) {
        int row = wr * 64 + i * 16 + l15;
        af[i] = *(const bf16x8*)(As + row * 128 + ((kb ^ (row & 7)) << 4));
      }
#pragma unroll
      for (int j = 0; j < 4; ++j) {
        int col = wc * 64 + j * 16 + l15;
        bfv[j] = *(const bf16x8*)(Bs + col * 128 + ((kb ^ (col & 7)) << 4));
      }
#pragma unroll
      for (int i = 0; i < 4; ++i)
#pragma unroll
        for (int j = 0; j < 4; ++j)
          acc[i][j] = __builtin_amdgcn_mfma_f32_16x16x32_bf16(af[i], bfv[j], acc[i][j], 0, 0, 0);
    }
    __syncthreads();
  }

  const int l4 = lane >> 4;
  float bcv[4];
#pragma unroll
  for (int j = 0; j < 4; ++j) bcv[j] = bc[n0 + wc * 64 + j * 16 + l15];
#pragma unroll
  for (int i = 0; i < 4; ++i) {
    int R = r0 + wr * 64 + i * 16 + l4 * 4;
#pragma unroll
    for (int q = 0; q < 4; ++q) {
      if (R + q < NE) {
#pragma unroll
        for (int j = 0; j < 4; ++j) {
          int col = n0 + wc * 64 + j * 16 + l15;
          m[(size_t)(R + q) * 384 + col] = (bf16)(acc[i][j][q] + bcv[j]);
        }
      }
    }
  }
}

// per-node segment stats; writes AGG bf16: aggbf[n][t*304 + {0,75,150,225}+g] = mean|mn|mx|std
__global__ __launch_bounds__(384) void k_agg(const bf16* __restrict__ m, const int* __restrict__ rowptr,
                                             bf16* __restrict__ aggbf) {
  int n = blockIdx.x;
  int c = threadIdx.x;
  if (c >= 375) return;
  int r0 = rowptr[n], r1 = rowptr[n + 1];
  float s = 0.f, s2 = 0.f, mn = INFINITY, mx = -INFINITY;
  for (int r = r0; r < r1; ++r) {
    float v = (float)m[(size_t)r * 384 + c];
    s += v; s2 += v * v;
    mn = fminf(mn, v); mx = fmaxf(mx, v);
  }
  int d = r1 - r0;
  float cnt1 = (d > 0) ? (float)d : 1.f;
  float mean = s / cnt1, msq = s2 / cnt1;
  float var = msq - mean * mean;
  if (var < 0.f) var = 0.f;
  float sd = sqrtf(var + 1e-5f);
  if (d == 0) { mn = 0.f; mx = 0.f; }
  int tt = c / FD, g = c - tt * FD;
  bf16* ag = aggbf + (size_t)n * 1520 + tt * 304;
  ag[g] = (bf16)mean; ag[75 + g] = (bf16)mn; ag[150 + g] = (bf16)mx; ag[225 + g] = (bf16)sd;
}

// Fold post_w@lin_w into Wct2[col 0..255][k_stored 0..1599] bf16, pre-swizzled.
// A-layout K: [0,75) h | pad | 80+t*304+{s2<300: stat*75+g} | pads -> zero rows.
// Output cols: group g2 in {id,amp,att} at g2*80 + o (o<75).
__global__ __launch_bounds__(256) void k_combine2(const float* __restrict__ pw,
    const float* __restrict__ lw, bf16* __restrict__ Wct2) {
  int idx = blockIdx.x * 256 + threadIdx.x;
  if (idx >= 256 * 1600) return;
  int c = idx / 1600, s = idx - c * 1600;
  int chunk = s >> 6, within = s & 63, sblk = within >> 3, elem = within & 7;
  int lb = sblk ^ (c & 7);
  int k = chunk * 64 + lb * 8 + elem;
  int g2 = c / 80, o = c - g2 * 80;
  float val = 0.f;
  if (c < 240 && o < 75) {
    if (k < 75) {
      if (g2 == 0) {
        for (int t = 0; t < 5; ++t)
          for (int j = 0; j < 15; ++j)
            val += pw[(t * 975 + k) * 15 + j] * lw[(t * 15 + j) * 75 + o];
      }
    } else if (k >= 80) {
      int q = k - 80;
      int t = q / 304, s2 = q - t * 304;
      if (s2 < 300) {
        int row = 75 + g2 * 300 + s2;
        for (int j = 0; j < 15; ++j)
          val += pw[(t * 975 + row) * 15 + j] * lw[(t * 15 + j) * 75 + o];
      }
    }
  }
  Wct2[(size_t)c * 1600 + s] = (bf16)val;
}

__global__ __launch_bounds__(128) void k_zbias(const float* __restrict__ pb,
    const float* __restrict__ lw, const float* __restrict__ lb, float* __restrict__ zb) {
  int o = blockIdx.x * 128 + threadIdx.x;
  if (o >= 75) return;
  float val = lb[o];
  for (int t = 0; t < 5; ++t)
    for (int j = 0; j < 15; ++j)
      val += pb[t * 15 + j] * lw[(t * 15 + j) * 75 + o];
  zb[o] = val;
}

// z[n][75] = P0 + scl*P1 + iscl*P2 + zb, P = [hbf|aggbf] (K=1600) @ Wct2 via MFMA.
// BM=32, BN=256 (3 groups of 80 + pad), 4 waves each 64 cols.
__global__ __launch_bounds__(256) void k_post2(const bf16* __restrict__ hbf,
    const bf16* __restrict__ aggbf, const bf16* __restrict__ Wct2, const float* __restrict__ zb,
    const float* __restrict__ scl, const float* __restrict__ iscl,
    const bf16* __restrict__ zerobuf, float* __restrict__ z) {
  __shared__ __align__(16) unsigned char smem[4096 + 32768];
  unsigned char* As = smem;
  unsigned char* Bs = smem + 4096;
  const int n0 = blockIdx.x * 32;
  const int tid = threadIdx.x;
  const int lane = tid & 63, wave = tid >> 6;
  const int l15 = lane & 15, l4 = lane >> 4;
  const int sr = tid >> 3, slb = tid & 7;
  f32x4 acc[2][4];
  f32x4 zv = {0.f, 0.f, 0.f, 0.f};
#pragma unroll
  for (int i = 0; i < 2; ++i)
#pragma unroll
    for (int j = 0; j < 4; ++j) acc[i][j] = zv;

  for (int c = 0; c < 25; ++c) {
    {
      int n = n0 + sr;
      int g = c * 8 + slb;
      const bf16* p;
      if (n < NN) p = (g < 10) ? (hbf + n * 80 + g * 8) : (aggbf + (size_t)n * 1520 + (g - 10) * 8);
      else        p = zerobuf;
      uint4 va = *(const uint4*)p;
      *(uint4*)(As + sr * 128 + ((slb ^ (sr & 7)) << 4)) = va;
    }
#pragma unroll
    for (int o = 0; o < 8; ++o) {
      int col = o * 32 + sr;
      uint4 vb = *(const uint4*)(Wct2 + (size_t)col * 1600 + c * 64 + slb * 8);
      *(uint4*)(Bs + col * 128 + (slb << 4)) = vb;
    }
    __syncthreads();
#pragma unroll
    for (int kk = 0; kk < 2; ++kk) {
      int kb = kk * 4 + l4;
      bf16x8 af[2], bv[4];
#pragma unroll
      for (int i = 0; i < 2; ++i) {
        int row = i * 16 + l15;
        af[i] = *(const bf16x8*)(As + row * 128 + ((kb ^ (row & 7)) << 4));
      }
#pragma unroll
      for (int j = 0; j < 4; ++j) {
        int col = wave * 64 + j * 16 + l15;
        bv[j] = *(const bf16x8*)(Bs + col * 128 + ((kb ^ (col & 7)) << 4));
      }
#pragma unroll
      for (int i = 0; i < 2; ++i)
#pragma unroll
        for (int j = 0; j < 4; ++j)
          acc[i][j] = __builtin_amdgcn_mfma_f32_16x16x32_bf16(af[i], bv[j], acc[i][j], 0, 0, 0);
    }
    __syncthreads();
  }

  float* Ps = (float*)Bs;   // 32*256*4 = 32768 B, fits exactly
#pragma unroll
  for (int i = 0; i < 2; ++i) {
    int r = i * 16 + l4 * 4;
#pragma unroll
    for (int j = 0; j < 4; ++j) {
      int col = wave * 64 + j * 16 + l15;
#pragma unroll
      for (int q = 0; q < 4; ++q) Ps[(r + q) * 256 + col] = acc[i][j][q];
    }
  }
  __syncthreads();
  for (int idx = tid; idx < 32 * 75; idx += 256) {
    int r = idx / 75, f = idx - r * 75;
    int n = n0 + r;
    if (n < NN) {
      float v = Ps[r * 256 + f] + scl[n] * Ps[r * 256 + 80 + f] + iscl[n] * Ps[r * 256 + 160 + f] + zb[f];
      z[n * 75 + f] = v;
    }
  }
}

// coalesced BN partial sums: block = 64-node chunk, LDS transpose, atomics into stat_raw[150]
__global__ __launch_bounds__(256) void k_bnsum(const float* __restrict__ z, float* __restrict__ stat_raw) {
  __shared__ float T[64 * 76];
  const int tid = threadIdx.x;
  const int n0 = blockIdx.x * 64;
  for (int idx = tid; idx < 64 * 75; idx += 256) {
    int flat = n0 * 75 + idx;
    float v = (flat < NN * 75) ? z[flat] : 0.f;
    int r = idx / 75, f = idx - r * 75;
    T[r * 76 + f] = v;
  }
  __syncthreads();
  if (tid < 75) {
    float s = 0.f, s2 = 0.f;
#pragma unroll
    for (int r = 0; r < 64; ++r) {
      float v = T[r * 76 + tid];
      s += v; s2 += v * v;
    }
    atomicAdd(&stat_raw[tid], s);
    atomicAdd(&stat_raw[75 + tid], s2);
  }
}

__global__ __launch_bounds__(256) void k_bnapply(const float* __restrict__ z,
    const float* __restrict__ stat_raw, const float* __restrict__ g, const float* __restrict__ b,
    float* __restrict__ outF, bf16* __restrict__ hbf) {
  int idx = blockIdx.x * 256 + threadIdx.x;
  if (idx >= NN * FD) return;
  int n = idx / FD, f = idx - n * FD;
  float mu = stat_raw[f] * (1.f / NN);
  float var = stat_raw[75 + f] * (1.f / NN) - mu * mu;
  var = fmaxf(var, 0.f);
  float rs = 1.f / sqrtf(var + 1e-5f);
  float v = (z[idx] - mu) * rs * g[f] + b[f];
  v = fmaxf(v, 0.f);
  outF[idx] = v;
  hbf[n * 80 + f] = (bf16)v;
}

__global__ __launch_bounds__(256) void k_pool(const float* __restrict__ h, const int* __restrict__ batch,
                                              float* __restrict__ gpool) {
  int idx = blockIdx.x * 256 + threadIdx.x;
  if (idx >= NN * FD) return;
  int n = idx / FD, f = idx - n * FD;
  atomicAdd(&gpool[batch[n] * FD + f], h[idx]);
}

__global__ __launch_bounds__(256) void k_mlp(const float* __restrict__ gpool,
    const float* __restrict__ w1, const float* __restrict__ b1,
    const float* __restrict__ w2, const float* __restrict__ b2,
    const float* __restrict__ w3, const float* __restrict__ b3,
    float* __restrict__ out) {
  __shared__ float G[NGR * FD];
  __shared__ float G1[NGR * 50];
  __shared__ float G2[NGR * 25];
  int tid = threadIdx.x;
  for (int i = tid; i < NGR * FD; i += 256) G[i] = gpool[i];
  __syncthreads();
  for (int i = tid; i < NGR * 50; i += 256) {
    int r = i / 50, c = i - r * 50;
    float a = b1[c];
    for (int k = 0; k < FD; ++k) a += G[r * FD + k] * w1[k * 50 + c];
    G1[i] = fmaxf(a, 0.f);
  }
  __syncthreads();
  for (int i = tid; i < NGR * 25; i += 256) {
    int r = i / 25, c = i - r * 25;
    float a = b2[c];
    for (int k = 0; k < 50; ++k) a += G1[r * 50 + k] * w2[k * 25 + c];
    G2[i] = fmaxf(a, 0.f);
  }
  __syncthreads();
  if (tid < NGR) {
    float a = b3[0];
    for (int k = 0; k < 25; ++k) a += G2[tid * 25 + k] * w3[k];
    out[tid] = a;
  }
}

// ---------------------------------------------------------------- host

extern "C" void kernel_launch(void* const* d_in, const int* in_sizes, int n_in,
                              void* d_out, int out_size, void* d_ws, size_t ws_size,
                              hipStream_t stream) {
  (void)in_sizes; (void)n_in; (void)out_size; (void)ws_size;
  const float* x      = (const float*)d_in[0];
  const int*   eidx   = (const int*)  d_in[1];
  const float* eattr  = (const float*)d_in[2];
  const int*   batch  = (const int*)  d_in[3];
  const float* nw     = (const float*)d_in[4];
  const float* nb     = (const float*)d_in[5];
  const float* ew     = (const float*)d_in[6];
  const float* ebias  = (const float*)d_in[7];
  const float* ee_w   = (const float*)d_in[8];
  const float* ee_b   = (const float*)d_in[9];
  const float* pre_w  = (const float*)d_in[10];
  const float* pre_b  = (const float*)d_in[11];
  const float* post_w = (const float*)d_in[12];
  const float* post_b = (const float*)d_in[13];
  const float* lin_w  = (const float*)d_in[14];
  const float* lin_b  = (const float*)d_in[15];
  const float* bn_g   = (const float*)d_in[16];
  const float* bn_b   = (const float*)d_in[17];
  const float* w1 = (const float*)d_in[18];
  const float* b1 = (const float*)d_in[19];
  const float* w2 = (const float*)d_in[20];
  const float* b2 = (const float*)d_in[21];
  const float* w3 = (const float*)d_in[22];
  const float* b3 = (const float*)d_in[23];

  const int* srcA = eidx;
  const int* dstA = eidx + NE;

  char* base = (char*)d_ws;
  size_t off = 0;
  auto alloc = [&](size_t bytes) -> char* {
    char* p = base + off;
    off = (off + bytes + 255) & ~(size_t)255;
    return p;
  };
  bf16*  hbf   = (bf16*) alloc((size_t)NN * 80 * 2);
  bf16*  eabf  = (bf16*) alloc((size_t)NE * 56 * 2);
  bf16*  mbf   = (bf16*) alloc((size_t)NE * 384 * 2);
  bf16*  aggbf = (bf16*) alloc((size_t)NN * 1520 * 2);
  float* z     = (float*)alloc((size_t)NN * FD * 4);
  float* hdump = (float*)alloc((size_t)NN * FD * 4);
  bf16*  Wct   = (bf16*) alloc((size_t)384 * 256 * 2);
  float* bc    = (float*)alloc(384 * 4);
  bf16*  Wct2  = (bf16*) alloc((size_t)256 * 1600 * 2);
  float* zb    = (float*)alloc(80 * 4);
  float* scl   = (float*)alloc(NN * 4);
  float* iscl  = (float*)alloc(NN * 4);
  int*   deg   = (int*)alloc(NN * 4);
  int*   rowptr= (int*)alloc((NN + 1) * 4);
  int*   cursor= (int*)alloc(NN * 4);
  int*   eids  = (int*)alloc(NE * 4);
  float* stat_raw = (float*)alloc(2 * FD * 4);
  float* gpool = (float*)alloc(NGR * FD * 4);
  bf16*  zerobuf = (bf16*)alloc(256);

  static const int DEG_TAB[71] = {1, 72, 201, 816, 1790, 3756, 6923, 12768, 20286, 31710,
    51623, 82296, 124280, 177576, 251115, 326064, 395760, 456840, 506179, 516200, 507003,
    493746, 489256, 453936, 420025, 411320, 427761, 420700, 420500, 426780, 414284, 407008,
    394053, 360910, 322245, 313704, 282902, 270940, 237783, 209000, 193766, 177870, 162110,
    144848, 121230, 112700, 93483, 88512, 72275, 80700, 68799, 56784, 42665, 30996, 25630,
    12936, 9804, 8584, 5251, 3480, 3111, 2728, 1890, 1472, 1235, 330, 201, 68, 69, 0, 71};
  double num = 0.0, den = 0.0;
  for (int i = 0; i < 71; ++i) { num += log((double)i + 1.0) * DEG_TAB[i]; den += DEG_TAB[i]; }
  float inv_avg_log = (float)(den / num);

  hipMemsetAsync(deg, 0, NN * 4, stream);
  hipMemsetAsync(cursor, 0, NN * 4, stream);
  hipMemsetAsync(gpool, 0, NGR * FD * 4, stream);
  hipMemsetAsync(zerobuf, 0, 256, stream);

  k_node_emb<<<(NN * FD + 255) / 256, 256, 0, stream>>>(x, nw, nb, hbf);
  k_edge_emb<<<(NE * 50 + 255) / 256, 256, 0, stream>>>(eattr, ew, ebias, eabf);
  k_count<<<(NE + 255) / 256, 256, 0, stream>>>(dstA, deg);
  k_scan<<<1, 1024, 0, stream>>>(deg, rowptr);
  k_scl<<<(NN + 255) / 256, 256, 0, stream>>>(deg, scl, iscl, inv_avg_log);
  k_scatter<<<(NE + 255) / 256, 256, 0, stream>>>(dstA, rowptr, cursor, eids);

  float* outp = (float*)d_out;
  for (int l = 0; l < NLAY; ++l) {
    k_combine<<<384, 256, 0, stream>>>(
        pre_w + (size_t)l * NT * 225 * FD, pre_b + (size_t)l * NT * FD,
        ee_w + (size_t)l * 50 * FD, ee_b + (size_t)l * FD, Wct, bc);
    dim3 gpre((NE + 127) / 128, 3);
    k_pre_mfma<<<gpre, 256, 0, stream>>>(hbf, eabf, eids, srcA, dstA, Wct, bc, zerobuf, mbf);
    k_agg<<<NN, 384, 0, stream>>>(mbf, rowptr, aggbf);
    k_combine2<<<1600, 256, 0, stream>>>(post_w + (size_t)l * NT * 975 * FOUT,
        lin_w + (size_t)l * FD * FD, Wct2);
    k_zbias<<<1, 128, 0, stream>>>(post_b + (size_t)l * NT * FOUT,
        lin_w + (size_t)l * FD * FD, lin_b + (size_t)l * FD, zb);
    k_post2<<<(NN + 31) / 32, 256, 0, stream>>>(hbf, aggbf, Wct2, zb, scl, iscl, zerobuf, z);
    hipMemsetAsync(stat_raw, 0, 2 * FD * 4, stream);
    k_bnsum<<<(NN + 63) / 64, 256, 0, stream>>>(z, stat_raw);
    float* wdst = (l == NLAY - 1) ? (outp + NGR) : hdump;
    k_bnapply<<<(NN * FD + 255) / 256, 256, 0, stream>>>(z, stat_raw, bn_g + (size_t)l * FD,
        bn_b + (size_t)l * FD, wdst, hbf);
  }

  k_pool<<<(NN * FD + 255) / 256, 256, 0, stream>>>(outp + NGR, batch, gpool);
  k_mlp<<<1, 256, 0, stream>>>(gpool, w1, b1, w2, b2, w3, b3, outp);
}

// Round 4
// 1020.133 us; speedup vs baseline: 2.7558x; 1.0135x over previous
//
#include <hip/hip_runtime.h>
#include <math.h>

#define NN 10000
#define NE 100000
#define NGR 64
#define NT 5
#define FD 75
#define FOUT 15
#define NLAY 4

typedef __bf16 bf16;
typedef __bf16 bf16x8 __attribute__((ext_vector_type(8)));
typedef float f32x4 __attribute__((ext_vector_type(4)));

// ---------------------------------------------------------------- small prep

__global__ __launch_bounds__(256) void k_node_emb(const float* __restrict__ x,
    const float* __restrict__ w, const float* __restrict__ b, bf16* __restrict__ hbf) {
  int idx = blockIdx.x * 256 + threadIdx.x;
  if (idx >= NN * FD) return;
  int n = idx / FD, f = idx - n * FD;
  float acc = b[f];
#pragma unroll
  for (int k = 0; k < 14; ++k) acc += x[n * 14 + k] * w[k * FD + f];
  hbf[n * 80 + f] = (bf16)acc;
}

__global__ __launch_bounds__(256) void k_edge_emb(const float* __restrict__ eattr,
    const float* __restrict__ w, const float* __restrict__ b, bf16* __restrict__ eabf) {
  int idx = blockIdx.x * 256 + threadIdx.x;
  if (idx >= NE * 50) return;
  int e = idx / 50, c = idx - e * 50;
  float acc = b[c];
#pragma unroll
  for (int k = 0; k < 4; ++k) acc += eattr[e * 4 + k] * w[k * 50 + c];
  eabf[e * 56 + c] = (bf16)acc;
}

__global__ __launch_bounds__(256) void k_count(const int* __restrict__ dst, int* __restrict__ deg) {
  int e = blockIdx.x * 256 + threadIdx.x;
  if (e < NE) atomicAdd(&deg[dst[e]], 1);
}

__global__ __launch_bounds__(1024) void k_scan(const int* __restrict__ deg, int* __restrict__ rowptr) {
  __shared__ int buf[1024];
  __shared__ int carry;
  int tid = threadIdx.x;
  if (tid == 0) carry = 0;
  __syncthreads();
  for (int base = 0; base < NN; base += 1024) {
    int i = base + tid;
    int v = (i < NN) ? deg[i] : 0;
    buf[tid] = v;
    __syncthreads();
    for (int off = 1; off < 1024; off <<= 1) {
      int t = (tid >= off) ? buf[tid - off] : 0;
      __syncthreads();
      buf[tid] += t;
      __syncthreads();
    }
    int inc = buf[tid];
    int tot = buf[1023];
    if (i < NN) rowptr[i + 1] = carry + inc;
    __syncthreads();
    if (tid == 0) carry += tot;
    __syncthreads();
  }
  if (tid == 0) rowptr[0] = 0;
}

__global__ __launch_bounds__(256) void k_scl(const int* __restrict__ deg, float* __restrict__ scl,
                                             float* __restrict__ iscl, float inv_avg_log) {
  int n = blockIdx.x * 256 + threadIdx.x;
  if (n >= NN) return;
  float c1 = fmaxf((float)deg[n], 1.f);
  float s = logf(c1 + 1.f) * inv_avg_log;
  scl[n] = s;
  iscl[n] = 1.f / s;
}

__global__ __launch_bounds__(256) void k_scatter(const int* __restrict__ dst, const int* __restrict__ rowptr,
    int* __restrict__ cursor, int* __restrict__ eids) {
  int e = blockIdx.x * 256 + threadIdx.x;
  if (e >= NE) return;
  int d = dst[e];
  int pos = rowptr[d] + atomicAdd(&cursor[d], 1);
  eids[pos] = e;
}

// ---------------------------------------------------------------- weight prep (hoisted)

// Wct[col 0..383][k_stored 0..255] bf16, pre-transposed + pre-swizzled.
// logical K: [0,75) h_dst | [80,155) h_src | [160,210) folded edge-encoder | else 0.
__global__ __launch_bounds__(256) void k_combine(const float* __restrict__ pre_w,
    const float* __restrict__ pre_b, const float* __restrict__ ee_w, const float* __restrict__ ee_b,
    bf16* __restrict__ Wct, float* __restrict__ bc) {
  int idx = blockIdx.x * 256 + threadIdx.x;
  if (idx >= 384 * 256) return;
  int c = idx >> 8, s = idx & 255;
  int t = c / 75, g = c - t * 75;
  int chunk = s >> 6, within = s & 63, sblk = within >> 3, elem = within & 7;
  int lb = sblk ^ (c & 7);
  int k = chunk * 64 + lb * 8 + elem;
  float v = 0.f;
  if (c < 375) {
    if (k < 75)                    v = pre_w[(t * 225 + k) * 75 + g];
    else if (k >= 80 && k < 155)   v = pre_w[(t * 225 + 75 + (k - 80)) * 75 + g];
    else if (k >= 160 && k < 210) {
      int kk = k - 160;
      float a = 0.f;
      for (int f2 = 0; f2 < 75; ++f2) a += ee_w[kk * 75 + f2] * pre_w[(t * 225 + 150 + f2) * 75 + g];
      v = a;
    }
  }
  Wct[c * 256 + s] = (bf16)v;
  if (s == 0) {
    float a = 0.f;
    if (c < 375) {
      a = pre_b[t * 75 + g];
      for (int f2 = 0; f2 < 75; ++f2) a += ee_b[f2] * pre_w[(t * 225 + 150 + f2) * 75 + g];
    }
    bc[c] = a;
  }
}

// PL[t][row 0..974][o 0..79] = sum_j post_w[t][row][j] * lin_w[t*15+j][o]   (o<75)
__global__ __launch_bounds__(256) void k_PL(const float* __restrict__ pw,
    const float* __restrict__ lw, float* __restrict__ PL) {
  int idx = blockIdx.x * 256 + threadIdx.x;
  if (idx >= 5 * 975 * 80) return;
  int t = idx / (975 * 80), rem = idx - t * 975 * 80;
  int row = rem / 80, o = rem - row * 80;
  float v = 0.f;
  if (o < 75) {
#pragma unroll
    for (int j = 0; j < 15; ++j)
      v += pw[((size_t)t * 975 + row) * 15 + j] * lw[(t * 15 + j) * 75 + o];
  }
  PL[idx] = v;
}

// Wct2[col 0..255][k_stored 0..1663] bf16, pre-swizzled gather of PL.
// A-layout K: [0,80) h(pad80) | 80 + si*384 + c  (si=mean,mn,mx,std; c<375 valid) | tail 0.
__global__ __launch_bounds__(256) void k_combine2b(const float* __restrict__ PL,
    bf16* __restrict__ Wct2) {
  int idx = blockIdx.x * 256 + threadIdx.x;
  if (idx >= 256 * 1664) return;
  int c = idx / 1664, s = idx - c * 1664;
  int chunk = s >> 6, within = s & 63, sblk = within >> 3, elem = within & 7;
  int lb = sblk ^ (c & 7);
  int k = chunk * 64 + lb * 8 + elem;
  int g2 = c / 80, o = c - g2 * 80;
  float val = 0.f;
  if (c < 240 && o < 75) {
    if (k < 75) {
      if (g2 == 0) {
#pragma unroll
        for (int t = 0; t < 5; ++t) val += PL[(t * 975 + k) * 80 + o];
      }
    } else if (k >= 80 && k < 1616) {
      int q = k - 80;
      int si = q / 384, cc = q - si * 384;
      if (cc < 375) {
        int t = cc / 75, g = cc - t * 75;
        int row = 75 + g2 * 300 + si * 75 + g;
        val = PL[((size_t)t * 975 + row) * 80 + o];
      }
    }
  }
  Wct2[(size_t)c * 1664 + s] = (bf16)val;
}

__global__ __launch_bounds__(128) void k_zbias(const float* __restrict__ pb,
    const float* __restrict__ lw, const float* __restrict__ lb, float* __restrict__ zb) {
  int o = blockIdx.x * 128 + threadIdx.x;
  if (o >= 80) return;
  float val = 0.f;
  if (o < 75) {
    val = lb[o];
    for (int t = 0; t < 5; ++t)
      for (int j = 0; j < 15; ++j)
        val += pb[t * 15 + j] * lw[(t * 15 + j) * 75 + o];
  }
  zb[o] = val;
}

// ---------------------------------------------------------------- main chain

// m[r][c] (bf16, stride 384) = A[r][0:256] @ Wct^T + bc, rows in CSR order.
__global__ __launch_bounds__(256) void k_pre_mfma(
    const bf16* __restrict__ hbf, const bf16* __restrict__ eabf,
    const int* __restrict__ eids, const int* __restrict__ srcA, const int* __restrict__ dstA,
    const bf16* __restrict__ Wct, const float* __restrict__ bc,
    const bf16* __restrict__ zerobuf, bf16* __restrict__ m) {
  __shared__ __align__(16) unsigned char As[16384];
  __shared__ __align__(16) unsigned char Bs[16384];
  __shared__ const bf16* pD[128];
  __shared__ const bf16* pS[128];
  __shared__ const bf16* pE[128];
  const int r0 = blockIdx.x * 128;
  const int n0 = blockIdx.y * 128;
  const int tid = threadIdx.x;
  if (tid < 128) {
    int R = r0 + tid;
    if (R < NE) {
      int e = eids[R];
      pD[tid] = hbf + dstA[e] * 80;
      pS[tid] = hbf + srcA[e] * 80;
      pE[tid] = eabf + e * 56;
    } else { pD[tid] = zerobuf; pS[tid] = zerobuf; pE[tid] = zerobuf; }
  }
  __syncthreads();
  const int lane = tid & 63;
  const int wave = tid >> 6;
  const int wr = wave >> 1, wc = wave & 1;
  const int l15 = lane & 15;
  f32x4 acc[4][4];
  f32x4 zv = {0.f, 0.f, 0.f, 0.f};
#pragma unroll
  for (int i = 0; i < 4; ++i)
#pragma unroll
    for (int j = 0; j < 4; ++j) acc[i][j] = zv;

  const int sr = tid >> 3;
  const int slb = tid & 7;

  for (int c = 0; c < 4; ++c) {
#pragma unroll
    for (int o = 0; o < 4; ++o) {
      int r = o * 32 + sr;
      int g = c * 8 + slb;
      const bf16* p;
      if (g < 10)      p = pD[r] + g * 8;
      else if (g < 20) p = pS[r] + (g - 10) * 8;
      else if (g < 27) p = pE[r] + (g - 20) * 8;
      else             p = zerobuf;
      uint4 va = *(const uint4*)p;
      *(uint4*)(As + r * 128 + ((slb ^ (r & 7)) << 4)) = va;
      uint4 vb = *(const uint4*)(Wct + (n0 + r) * 256 + c * 64 + slb * 8);
      *(uint4*)(Bs + r * 128 + (slb << 4)) = vb;
    }
    __syncthreads();
#pragma unroll
    for (int kk = 0; kk < 2; ++kk) {
      int kb = kk * 4 + (lane >> 4);
      bf16x8 af[4], bfv[4];
#pragma unroll
      for (int i = 0; i < 4; ++i) {
        int row = wr * 64 + i * 16 + l15;
        af[i] = *(const bf16x8*)(As + row * 128 + ((kb ^ (row & 7)) << 4));
      }
#pragma unroll
      for (int j = 0; j < 4; ++j) {
        int col = wc * 64 + j * 16 + l15;
        bfv[j] = *(const bf16x8*)(Bs + col * 128 + ((kb ^ (col & 7)) << 4));
      }
#pragma unroll
      for (int i = 0; i < 4; ++i)
#pragma unroll
        for (int j = 0; j < 4; ++j)
          acc[i][j] = __builtin_amdgcn_mfma_f32_16x16x32_bf16(af[i], bfv[j], acc[i][j], 0, 0, 0);
    }
    __syncthreads();
  }

  const int l4 = lane >> 4;
  float bcv[4];
#pragma unroll
  for (int j = 0; j < 4; ++j) bcv[j] = bc[n0 + wc * 64 + j * 16 + l15];
#pragma unroll
  for (int i = 0; i < 4; ++i) {
    int R = r0 + wr * 64 + i * 16 + l4 * 4;
#pragma unroll
    for (int q = 0; q < 4; ++q) {
      if (R + q < NE) {
#pragma unroll
        for (int j = 0; j < 4; ++j) {
          int col = n0 + wc * 64 + j * 16 + l15;
          m[(size_t)(R + q) * 384 + col] = (bf16)(acc[i][j][q] + bcv[j]);
        }
      }
    }
  }
}

// vectorized per-node stats; aggbf2[n][si*384 + c] bf16, si = mean|mn|mx|std
// block: 8 nodes x 48 col-chunks (bf16x8); grid 1250
__global__ __launch_bounds__(384) void k_agg2(const bf16* __restrict__ m,
    const int* __restrict__ rowptr, bf16* __restrict__ aggbf2) {
  const int tid = threadIdx.x;
  const int node_local = tid / 48, cw = tid - node_local * 48;
  const int n = blockIdx.x * 8 + node_local;
  if (n >= NN) return;
  int r0 = rowptr[n], r1 = rowptr[n + 1];
  float s[8], s2[8], mn[8], mx[8];
#pragma unroll
  for (int j = 0; j < 8; ++j) { s[j] = 0.f; s2[j] = 0.f; mn[j] = INFINITY; mx[j] = -INFINITY; }
  for (int r = r0; r < r1; ++r) {
    bf16x8 v = *(const bf16x8*)(m + (size_t)r * 384 + cw * 8);
#pragma unroll
    for (int j = 0; j < 8; ++j) {
      float x = (float)v[j];
      s[j] += x; s2[j] += x * x;
      mn[j] = fminf(mn[j], x); mx[j] = fmaxf(mx[j], x);
    }
  }
  int d = r1 - r0;
  float cnt1 = (d > 0) ? (float)d : 1.f;
  float inv = 1.f / cnt1;
  bf16x8 vm, vmn, vmx, vsd;
#pragma unroll
  for (int j = 0; j < 8; ++j) {
    float mean = s[j] * inv, msq = s2[j] * inv;
    float var = msq - mean * mean;
    if (var < 0.f) var = 0.f;
    float sd = sqrtf(var + 1e-5f);
    float a = (d == 0) ? 0.f : mn[j];
    float b = (d == 0) ? 0.f : mx[j];
    vm[j] = (bf16)mean; vmn[j] = (bf16)a; vmx[j] = (bf16)b; vsd[j] = (bf16)sd;
  }
  bf16* ag = aggbf2 + (size_t)n * 1536 + cw * 8;
  *(bf16x8*)(ag) = vm;
  *(bf16x8*)(ag + 384) = vmn;
  *(bf16x8*)(ag + 768) = vmx;
  *(bf16x8*)(ag + 1152) = vsd;
}

// Pbuf[ks][n][240] += [hbf|aggbf2](K slice) @ Wct2 ; grid (313, 2), prefetch-pipelined.
__global__ __launch_bounds__(256) void k_post3(const bf16* __restrict__ hbf,
    const bf16* __restrict__ aggbf2, const bf16* __restrict__ Wct2,
    const bf16* __restrict__ zerobuf, float* __restrict__ Pbuf) {
  __shared__ __align__(16) unsigned char As[4096];
  __shared__ __align__(16) unsigned char Bs[32768];
  const int n0 = blockIdx.x * 32;
  const int ks = blockIdx.y;
  const int cbeg = ks * 13;
  const int tid = threadIdx.x;
  const int lane = tid & 63, wave = tid >> 6;
  const int l15 = lane & 15, l4 = lane >> 4;
  const int sr = tid >> 3, slb = tid & 7;
  f32x4 acc[2][4];
  f32x4 zv = {0.f, 0.f, 0.f, 0.f};
#pragma unroll
  for (int i = 0; i < 2; ++i)
#pragma unroll
    for (int j = 0; j < 4; ++j) acc[i][j] = zv;

  uint4 pa;
  uint4 pb[8];
  auto loadregs = [&](int c) {
    int n = n0 + sr;
    int g = c * 8 + slb;
    const bf16* p;
    if (n >= NN || g >= 202) p = zerobuf;
    else if (g < 10)         p = hbf + n * 80 + g * 8;
    else                     p = aggbf2 + (size_t)n * 1536 + (g - 10) * 8;
    pa = *(const uint4*)p;
#pragma unroll
    for (int o = 0; o < 8; ++o)
      pb[o] = *(const uint4*)(Wct2 + (size_t)(o * 32 + sr) * 1664 + c * 64 + slb * 8);
  };

  loadregs(cbeg);
  for (int i = 0; i < 13; ++i) {
    *(uint4*)(As + sr * 128 + ((slb ^ (sr & 7)) << 4)) = pa;
#pragma unroll
    for (int o = 0; o < 8; ++o)
      *(uint4*)(Bs + (o * 32 + sr) * 128 + (slb << 4)) = pb[o];
    __syncthreads();
    if (i < 12) loadregs(cbeg + i + 1);   // in flight during ds_read + MFMA
#pragma unroll
    for (int kk = 0; kk < 2; ++kk) {
      int kb = kk * 4 + l4;
      bf16x8 af[2], bv[4];
#pragma unroll
      for (int ii = 0; ii < 2; ++ii) {
        int row = ii * 16 + l15;
        af[ii] = *(const bf16x8*)(As + row * 128 + ((kb ^ (row & 7)) << 4));
      }
#pragma unroll
      for (int j = 0; j < 4; ++j) {
        int col = wave * 64 + j * 16 + l15;
        bv[j] = *(const bf16x8*)(Bs + col * 128 + ((kb ^ (col & 7)) << 4));
      }
#pragma unroll
      for (int ii = 0; ii < 2; ++ii)
#pragma unroll
        for (int j = 0; j < 4; ++j)
          acc[ii][j] = __builtin_amdgcn_mfma_f32_16x16x32_bf16(af[ii], bv[j], acc[ii][j], 0, 0, 0);
    }
    __syncthreads();
  }

#pragma unroll
  for (int ii = 0; ii < 2; ++ii) {
    int rbase = ii * 16 + l4 * 4;
#pragma unroll
    for (int j = 0; j < 4; ++j) {
      int col = wave * 64 + j * 16 + l15;
      if (col < 240) {
#pragma unroll
        for (int q = 0; q < 4; ++q) {
          int n = n0 + rbase + q;
          if (n < NN) Pbuf[((size_t)ks * NN + n) * 240 + col] = acc[ii][j][q];
        }
      }
    }
  }
}

// epilogue: z = (P0a+P0b) + scl*(P1a+P1b) + iscl*(P2a+P2b) + zb; fused BN partial sums.
__global__ __launch_bounds__(256) void k_zep(const float* __restrict__ Pbuf,
    const float* __restrict__ scl, const float* __restrict__ iscl, const float* __restrict__ zb,
    float* __restrict__ z, float* __restrict__ stat_raw) {
  __shared__ float T[64 * 76];
  const int tid = threadIdx.x;
  const int n0 = blockIdx.x * 64;
  for (int idx = tid; idx < 64 * 75; idx += 256) {
    int r = idx / 75, f = idx - r * 75;
    int n = n0 + r;
    float v = 0.f;
    if (n < NN) {
      const float* P0 = Pbuf + (size_t)n * 240;
      const float* P1 = Pbuf + (size_t)(NN + n) * 240;
      v = (P0[f] + P1[f]) + scl[n] * (P0[80 + f] + P1[80 + f])
        + iscl[n] * (P0[160 + f] + P1[160 + f]) + zb[f];
      z[n * 75 + f] = v;
    }
    T[r * 76 + f] = v;
  }
  __syncthreads();
  if (tid < 75) {
    float s = 0.f, s2 = 0.f;
#pragma unroll
    for (int r = 0; r < 64; ++r) {
      float v = T[r * 76 + tid];
      s += v; s2 += v * v;
    }
    atomicAdd(&stat_raw[tid], s);
    atomicAdd(&stat_raw[75 + tid], s2);
  }
}

__global__ __launch_bounds__(256) void k_bnapply(const float* __restrict__ z,
    const float* __restrict__ stat_raw, const float* __restrict__ g, const float* __restrict__ b,
    float* __restrict__ outF, bf16* __restrict__ hbf) {
  int idx = blockIdx.x * 256 + threadIdx.x;
  if (idx >= NN * FD) return;
  int n = idx / FD, f = idx - n * FD;
  float mu = stat_raw[f] * (1.f / NN);
  float var = stat_raw[75 + f] * (1.f / NN) - mu * mu;
  var = fmaxf(var, 0.f);
  float rs = 1.f / sqrtf(var + 1e-5f);
  float v = (z[idx] - mu) * rs * g[f] + b[f];
  v = fmaxf(v, 0.f);
  if (outF) outF[idx] = v;
  hbf[n * 80 + f] = (bf16)v;
}

__global__ __launch_bounds__(256) void k_pool(const float* __restrict__ h, const int* __restrict__ batch,
                                              float* __restrict__ gpool) {
  int idx = blockIdx.x * 256 + threadIdx.x;
  if (idx >= NN * FD) return;
  int n = idx / FD, f = idx - n * FD;
  atomicAdd(&gpool[batch[n] * FD + f], h[idx]);
}

__global__ __launch_bounds__(256) void k_mlp(const float* __restrict__ gpool,
    const float* __restrict__ w1, const float* __restrict__ b1,
    const float* __restrict__ w2, const float* __restrict__ b2,
    const float* __restrict__ w3, const float* __restrict__ b3,
    float* __restrict__ out) {
  __shared__ float G[NGR * FD];
  __shared__ float G1[NGR * 50];
  __shared__ float G2[NGR * 25];
  int tid = threadIdx.x;
  for (int i = tid; i < NGR * FD; i += 256) G[i] = gpool[i];
  __syncthreads();
  for (int i = tid; i < NGR * 50; i += 256) {
    int r = i / 50, c = i - r * 50;
    float a = b1[c];
    for (int k = 0; k < FD; ++k) a += G[r * FD + k] * w1[k * 50 + c];
    G1[i] = fmaxf(a, 0.f);
  }
  __syncthreads();
  for (int i = tid; i < NGR * 25; i += 256) {
    int r = i / 25, c = i - r * 25;
    float a = b2[c];
    for (int k = 0; k < 50; ++k) a += G1[r * 50 + k] * w2[k * 25 + c];
    G2[i] = fmaxf(a, 0.f);
  }
  __syncthreads();
  if (tid < NGR) {
    float a = b3[0];
    for (int k = 0; k < 25; ++k) a += G2[tid * 25 + k] * w3[k];
    out[tid] = a;
  }
}

// ---------------------------------------------------------------- host

extern "C" void kernel_launch(void* const* d_in, const int* in_sizes, int n_in,
                              void* d_out, int out_size, void* d_ws, size_t ws_size,
                              hipStream_t stream) {
  (void)in_sizes; (void)n_in; (void)out_size; (void)ws_size;
  const float* x      = (const float*)d_in[0];
  const int*   eidx   = (const int*)  d_in[1];
  const float* eattr  = (const float*)d_in[2];
  const int*   batch  = (const int*)  d_in[3];
  const float* nw     = (const float*)d_in[4];
  const float* nb     = (const float*)d_in[5];
  const float* ew     = (const float*)d_in[6];
  const float* ebias  = (const float*)d_in[7];
  const float* ee_w   = (const float*)d_in[8];
  const float* ee_b   = (const float*)d_in[9];
  const float* pre_w  = (const float*)d_in[10];
  const float* pre_b  = (const float*)d_in[11];
  const float* post_w = (const float*)d_in[12];
  const float* post_b = (const float*)d_in[13];
  const float* lin_w  = (const float*)d_in[14];
  const float* lin_b  = (const float*)d_in[15];
  const float* bn_g   = (const float*)d_in[16];
  const float* bn_b   = (const float*)d_in[17];
  const float* w1 = (const float*)d_in[18];
  const float* b1 = (const float*)d_in[19];
  const float* w2 = (const float*)d_in[20];
  const float* b2 = (const float*)d_in[21];
  const float* w3 = (const float*)d_in[22];
  const float* b3 = (const float*)d_in[23];

  const int* srcA = eidx;
  const int* dstA = eidx + NE;

  char* base = (char*)d_ws;
  size_t off = 0;
  auto alloc = [&](size_t bytes) -> char* {
    char* p = base + off;
    off = (off + bytes + 255) & ~(size_t)255;
    return p;
  };
  bf16*  hbf    = (bf16*) alloc((size_t)NN * 80 * 2);
  bf16*  eabf   = (bf16*) alloc((size_t)NE * 56 * 2);
  bf16*  mbf    = (bf16*) alloc((size_t)NE * 384 * 2);
  bf16*  aggbf2 = (bf16*) alloc((size_t)NN * 1536 * 2);
  float* z      = (float*)alloc((size_t)NN * FD * 4);
  float* Pbuf   = (float*)alloc((size_t)2 * NN * 240 * 4);
  bf16*  WctA   = (bf16*) alloc((size_t)NLAY * 384 * 256 * 2);
  float* bcA    = (float*)alloc((size_t)NLAY * 384 * 4);
  bf16*  Wct2A  = (bf16*) alloc((size_t)NLAY * 256 * 1664 * 2);
  float* zbA    = (float*)alloc((size_t)NLAY * 80 * 4);
  float* PL     = (float*)alloc((size_t)5 * 975 * 80 * 4);
  float* scl    = (float*)alloc(NN * 4);
  float* iscl   = (float*)alloc(NN * 4);
  int*   deg    = (int*)alloc(NN * 4);
  int*   rowptr = (int*)alloc((NN + 1) * 4);
  int*   cursor = (int*)alloc(NN * 4);
  int*   eids   = (int*)alloc(NE * 4);
  float* stat_raw = (float*)alloc(2 * FD * 4);
  float* gpool  = (float*)alloc(NGR * FD * 4);
  bf16*  zerobuf = (bf16*)alloc(256);

  static const int DEG_TAB[71] = {1, 72, 201, 816, 1790, 3756, 6923, 12768, 20286, 31710,
    51623, 82296, 124280, 177576, 251115, 326064, 395760, 456840, 506179, 516200, 507003,
    493746, 489256, 453936, 420025, 411320, 427761, 420700, 420500, 426780, 414284, 407008,
    394053, 360910, 322245, 313704, 282902, 270940, 237783, 209000, 193766, 177870, 162110,
    144848, 121230, 112700, 93483, 88512, 72275, 80700, 68799, 56784, 42665, 30996, 25630,
    12936, 9804, 8584, 5251, 3480, 3111, 2728, 1890, 1472, 1235, 330, 201, 68, 69, 0, 71};
  double num = 0.0, den = 0.0;
  for (int i = 0; i < 71; ++i) { num += log((double)i + 1.0) * DEG_TAB[i]; den += DEG_TAB[i]; }
  float inv_avg_log = (float)(den / num);

  hipMemsetAsync(deg, 0, NN * 4, stream);
  hipMemsetAsync(cursor, 0, NN * 4, stream);
  hipMemsetAsync(gpool, 0, NGR * FD * 4, stream);
  hipMemsetAsync(zerobuf, 0, 256, stream);

  // graph prep
  k_node_emb<<<(NN * FD + 255) / 256, 256, 0, stream>>>(x, nw, nb, hbf);
  k_edge_emb<<<(NE * 50 + 255) / 256, 256, 0, stream>>>(eattr, ew, ebias, eabf);
  k_count<<<(NE + 255) / 256, 256, 0, stream>>>(dstA, deg);
  k_scan<<<1, 1024, 0, stream>>>(deg, rowptr);
  k_scl<<<(NN + 255) / 256, 256, 0, stream>>>(deg, scl, iscl, inv_avg_log);
  k_scatter<<<(NE + 255) / 256, 256, 0, stream>>>(dstA, rowptr, cursor, eids);

  // weight prep, all layers up front
  for (int l = 0; l < NLAY; ++l) {
    k_combine<<<384, 256, 0, stream>>>(
        pre_w + (size_t)l * NT * 225 * FD, pre_b + (size_t)l * NT * FD,
        ee_w + (size_t)l * 50 * FD, ee_b + (size_t)l * FD,
        WctA + (size_t)l * 384 * 256, bcA + (size_t)l * 384);
    k_PL<<<(5 * 975 * 80 + 255) / 256, 256, 0, stream>>>(
        post_w + (size_t)l * NT * 975 * FOUT, lin_w + (size_t)l * FD * FD, PL);
    k_combine2b<<<(256 * 1664 + 255) / 256, 256, 0, stream>>>(PL, Wct2A + (size_t)l * 256 * 1664);
    k_zbias<<<1, 128, 0, stream>>>(post_b + (size_t)l * NT * FOUT,
        lin_w + (size_t)l * FD * FD, lin_b + (size_t)l * FD, zbA + (size_t)l * 80);
  }

  float* outp = (float*)d_out;
  for (int l = 0; l < NLAY; ++l) {
    dim3 gpre((NE + 127) / 128, 3);
    k_pre_mfma<<<gpre, 256, 0, stream>>>(hbf, eabf, eids, srcA, dstA,
        WctA + (size_t)l * 384 * 256, bcA + (size_t)l * 384, zerobuf, mbf);
    k_agg2<<<(NN + 7) / 8, 384, 0, stream>>>(mbf, rowptr, aggbf2);
    dim3 gpost((NN + 31) / 32, 2);
    k_post3<<<gpost, 256, 0, stream>>>(hbf, aggbf2, Wct2A + (size_t)l * 256 * 1664, zerobuf, Pbuf);
    hipMemsetAsync(stat_raw, 0, 2 * FD * 4, stream);
    k_zep<<<(NN + 63) / 64, 256, 0, stream>>>(Pbuf, scl, iscl, zbA + (size_t)l * 80, z, stat_raw);
    float* wdst = (l == NLAY - 1) ? (outp + NGR) : nullptr;
    k_bnapply<<<(NN * FD + 255) / 256, 256, 0, stream>>>(z, stat_raw, bn_g + (size_t)l * FD,
        bn_b + (size_t)l * FD, wdst, hbf);
  }

  k_pool<<<(NN * FD + 255) / 256, 256, 0, stream>>>(outp + NGR, batch, gpool);
  k_mlp<<<1, 256, 0, stream>>>(gpool, w1, b1, w2, b2, w3, b3, outp);
}

// Round 5
// 751.195 us; speedup vs baseline: 3.7424x; 1.3580x over previous
//
#include <hip/hip_runtime.h>
#include <math.h>

#define NN 10000
#define NE 100000
#define NGR 64
#define NT 5
#define FD 75
#define FOUT 15
#define NLAY 4

typedef __bf16 bf16;
typedef __bf16 bf16x8 __attribute__((ext_vector_type(8)));
typedef float f32x4 __attribute__((ext_vector_type(4)));

// ---------------------------------------------------------------- small prep

__global__ __launch_bounds__(256) void k_node_emb(const float* __restrict__ x,
    const float* __restrict__ w, const float* __restrict__ b, bf16* __restrict__ hbf) {
  int idx = blockIdx.x * 256 + threadIdx.x;
  if (idx >= NN * FD) return;
  int n = idx / FD, f = idx - n * FD;
  float acc = b[f];
#pragma unroll
  for (int k = 0; k < 14; ++k) acc += x[n * 14 + k] * w[k * FD + f];
  hbf[n * 80 + f] = (bf16)acc;
}

__global__ __launch_bounds__(256) void k_edge_emb(const float* __restrict__ eattr,
    const float* __restrict__ w, const float* __restrict__ b, bf16* __restrict__ eabf) {
  int idx = blockIdx.x * 256 + threadIdx.x;
  if (idx >= NE * 50) return;
  int e = idx / 50, c = idx - e * 50;
  float acc = b[c];
#pragma unroll
  for (int k = 0; k < 4; ++k) acc += eattr[e * 4 + k] * w[k * 50 + c];
  eabf[e * 56 + c] = (bf16)acc;
}

__global__ __launch_bounds__(256) void k_count(const int* __restrict__ dst, int* __restrict__ deg) {
  int e = blockIdx.x * 256 + threadIdx.x;
  if (e < NE) atomicAdd(&deg[dst[e]], 1);
}

__global__ __launch_bounds__(1024) void k_scan(const int* __restrict__ deg, int* __restrict__ rowptr) {
  __shared__ int buf[1024];
  __shared__ int carry;
  int tid = threadIdx.x;
  if (tid == 0) carry = 0;
  __syncthreads();
  for (int base = 0; base < NN; base += 1024) {
    int i = base + tid;
    int v = (i < NN) ? deg[i] : 0;
    buf[tid] = v;
    __syncthreads();
    for (int off = 1; off < 1024; off <<= 1) {
      int t = (tid >= off) ? buf[tid - off] : 0;
      __syncthreads();
      buf[tid] += t;
      __syncthreads();
    }
    int inc = buf[tid];
    int tot = buf[1023];
    if (i < NN) rowptr[i + 1] = carry + inc;
    __syncthreads();
    if (tid == 0) carry += tot;
    __syncthreads();
  }
  if (tid == 0) rowptr[0] = 0;
}

__global__ __launch_bounds__(256) void k_scl(const int* __restrict__ deg, float* __restrict__ scl,
                                             float* __restrict__ iscl, float inv_avg_log) {
  int n = blockIdx.x * 256 + threadIdx.x;
  if (n >= NN) return;
  float c1 = fmaxf((float)deg[n], 1.f);
  float s = logf(c1 + 1.f) * inv_avg_log;
  scl[n] = s;
  iscl[n] = 1.f / s;
}

__global__ __launch_bounds__(256) void k_scatter(const int* __restrict__ dst, const int* __restrict__ rowptr,
    int* __restrict__ cursor, int* __restrict__ eids) {
  int e = blockIdx.x * 256 + threadIdx.x;
  if (e >= NE) return;
  int d = dst[e];
  int pos = rowptr[d] + atomicAdd(&cursor[d], 1);
  eids[pos] = e;
}

// ---------------------------------------------------------------- weight prep (hoisted)

__global__ __launch_bounds__(256) void k_combine(const float* __restrict__ pre_w,
    const float* __restrict__ pre_b, const float* __restrict__ ee_w, const float* __restrict__ ee_b,
    bf16* __restrict__ Wct, float* __restrict__ bc) {
  int idx = blockIdx.x * 256 + threadIdx.x;
  if (idx >= 384 * 256) return;
  int c = idx >> 8, s = idx & 255;
  int t = c / 75, g = c - t * 75;
  int chunk = s >> 6, within = s & 63, sblk = within >> 3, elem = within & 7;
  int lb = sblk ^ (c & 7);
  int k = chunk * 64 + lb * 8 + elem;
  float v = 0.f;
  if (c < 375) {
    if (k < 75)                    v = pre_w[(t * 225 + k) * 75 + g];
    else if (k >= 80 && k < 155)   v = pre_w[(t * 225 + 75 + (k - 80)) * 75 + g];
    else if (k >= 160 && k < 210) {
      int kk = k - 160;
      float a = 0.f;
      for (int f2 = 0; f2 < 75; ++f2) a += ee_w[kk * 75 + f2] * pre_w[(t * 225 + 150 + f2) * 75 + g];
      v = a;
    }
  }
  Wct[c * 256 + s] = (bf16)v;
  if (s == 0) {
    float a = 0.f;
    if (c < 375) {
      a = pre_b[t * 75 + g];
      for (int f2 = 0; f2 < 75; ++f2) a += ee_b[f2] * pre_w[(t * 225 + 150 + f2) * 75 + g];
    }
    bc[c] = a;
  }
}

// PL[t][row 0..974][o 0..79] = sum_j post_w[t][row][j] * lin_w[t*15+j][o]   (o<75)
__global__ __launch_bounds__(256) void k_PL(const float* __restrict__ pw,
    const float* __restrict__ lw, float* __restrict__ PL) {
  int idx = blockIdx.x * 256 + threadIdx.x;
  if (idx >= 5 * 975 * 80) return;
  int t = idx / (975 * 80), rem = idx - t * 975 * 80;
  int row = rem / 80, o = rem - row * 80;
  float v = 0.f;
  if (o < 75) {
#pragma unroll
    for (int j = 0; j < 15; ++j)
      v += pw[((size_t)t * 975 + row) * 15 + j] * lw[(t * 15 + j) * 75 + o];
  }
  PL[idx] = v;
}

// Wct2[col 0..255][k_stored 0..1663] bf16, pre-swizzled gather of PL.
__global__ __launch_bounds__(256) void k_combine2b(const float* __restrict__ PL,
    bf16* __restrict__ Wct2) {
  int idx = blockIdx.x * 256 + threadIdx.x;
  if (idx >= 256 * 1664) return;
  int c = idx / 1664, s = idx - c * 1664;
  int chunk = s >> 6, within = s & 63, sblk = within >> 3, elem = within & 7;
  int lb = sblk ^ (c & 7);
  int k = chunk * 64 + lb * 8 + elem;
  int g2 = c / 80, o = c - g2 * 80;
  float val = 0.f;
  if (c < 240 && o < 75) {
    if (k < 75) {
      if (g2 == 0) {
#pragma unroll
        for (int t = 0; t < 5; ++t) val += PL[(t * 975 + k) * 80 + o];
      }
    } else if (k >= 80 && k < 1616) {
      int q = k - 80;
      int si = q / 384, cc = q - si * 384;
      if (cc < 375) {
        int t = cc / 75, g = cc - t * 75;
        int row = 75 + g2 * 300 + si * 75 + g;
        val = PL[((size_t)t * 975 + row) * 80 + o];
      }
    }
  }
  Wct2[(size_t)c * 1664 + s] = (bf16)val;
}

__global__ __launch_bounds__(128) void k_zbias(const float* __restrict__ pb,
    const float* __restrict__ lw, const float* __restrict__ lb, float* __restrict__ zb) {
  int o = blockIdx.x * 128 + threadIdx.x;
  if (o >= 80) return;
  float val = 0.f;
  if (o < 75) {
    val = lb[o];
    for (int t = 0; t < 5; ++t)
      for (int j = 0; j < 15; ++j)
        val += pb[t * 15 + j] * lw[(t * 15 + j) * 75 + o];
  }
  zb[o] = val;
}

// ---------------------------------------------------------------- main chain

__global__ __launch_bounds__(256) void k_pre_mfma(
    const bf16* __restrict__ hbf, const bf16* __restrict__ eabf,
    const int* __restrict__ eids, const int* __restrict__ srcA, const int* __restrict__ dstA,
    const bf16* __restrict__ Wct, const float* __restrict__ bc,
    const bf16* __restrict__ zerobuf, bf16* __restrict__ m) {
  __shared__ __align__(16) unsigned char As[16384];
  __shared__ __align__(16) unsigned char Bs[16384];
  __shared__ const bf16* pD[128];
  __shared__ const bf16* pS[128];
  __shared__ const bf16* pE[128];
  const int r0 = blockIdx.x * 128;
  const int n0 = blockIdx.y * 128;
  const int tid = threadIdx.x;
  if (tid < 128) {
    int R = r0 + tid;
    if (R < NE) {
      int e = eids[R];
      pD[tid] = hbf + dstA[e] * 80;
      pS[tid] = hbf + srcA[e] * 80;
      pE[tid] = eabf + e * 56;
    } else { pD[tid] = zerobuf; pS[tid] = zerobuf; pE[tid] = zerobuf; }
  }
  __syncthreads();
  const int lane = tid & 63;
  const int wave = tid >> 6;
  const int wr = wave >> 1, wc = wave & 1;
  const int l15 = lane & 15;
  f32x4 acc[4][4];
  f32x4 zv = {0.f, 0.f, 0.f, 0.f};
#pragma unroll
  for (int i = 0; i < 4; ++i)
#pragma unroll
    for (int j = 0; j < 4; ++j) acc[i][j] = zv;

  const int sr = tid >> 3;
  const int slb = tid & 7;

  for (int c = 0; c < 4; ++c) {
#pragma unroll
    for (int o = 0; o < 4; ++o) {
      int r = o * 32 + sr;
      int g = c * 8 + slb;
      const bf16* p;
      if (g < 10)      p = pD[r] + g * 8;
      else if (g < 20) p = pS[r] + (g - 10) * 8;
      else if (g < 27) p = pE[r] + (g - 20) * 8;
      else             p = zerobuf;
      uint4 va = *(const uint4*)p;
      *(uint4*)(As + r * 128 + ((slb ^ (r & 7)) << 4)) = va;
      uint4 vb = *(const uint4*)(Wct + (n0 + r) * 256 + c * 64 + slb * 8);
      *(uint4*)(Bs + r * 128 + (slb << 4)) = vb;
    }
    __syncthreads();
#pragma unroll
    for (int kk = 0; kk < 2; ++kk) {
      int kb = kk * 4 + (lane >> 4);
      bf16x8 af[4], bfv[4];
#pragma unroll
      for (int i = 0; i < 4; ++i) {
        int row = wr * 64 + i * 16 + l15;
        af[i] = *(const bf16x8*)(As + row * 128 + ((kb ^ (row & 7)) << 4));
      }
#pragma unroll
      for (int j = 0; j < 4; ++j) {
        int col = wc * 64 + j * 16 + l15;
        bfv[j] = *(const bf16x8*)(Bs + col * 128 + ((kb ^ (col & 7)) << 4));
      }
#pragma unroll
      for (int i = 0; i < 4; ++i)
#pragma unroll
        for (int j = 0; j < 4; ++j)
          acc[i][j] = __builtin_amdgcn_mfma_f32_16x16x32_bf16(af[i], bfv[j], acc[i][j], 0, 0, 0);
    }
    __syncthreads();
  }

  const int l4 = lane >> 4;
  float bcv[4];
#pragma unroll
  for (int j = 0; j < 4; ++j) bcv[j] = bc[n0 + wc * 64 + j * 16 + l15];
#pragma unroll
  for (int i = 0; i < 4; ++i) {
    int R = r0 + wr * 64 + i * 16 + l4 * 4;
#pragma unroll
    for (int q = 0; q < 4; ++q) {
      if (R + q < NE) {
#pragma unroll
        for (int j = 0; j < 4; ++j) {
          int col = n0 + wc * 64 + j * 16 + l15;
          m[(size_t)(R + q) * 384 + col] = (bf16)(acc[i][j][q] + bcv[j]);
        }
      }
    }
  }
}

// vectorized per-node stats; aggbf2[n][si*384 + c] bf16, si = mean|mn|mx|std
__global__ __launch_bounds__(384) void k_agg2(const bf16* __restrict__ m,
    const int* __restrict__ rowptr, bf16* __restrict__ aggbf2) {
  const int tid = threadIdx.x;
  const int node_local = tid / 48, cw = tid - node_local * 48;
  const int n = blockIdx.x * 8 + node_local;
  if (n >= NN) return;
  int r0 = rowptr[n], r1 = rowptr[n + 1];
  float s[8], s2[8], mn[8], mx[8];
#pragma unroll
  for (int j = 0; j < 8; ++j) { s[j] = 0.f; s2[j] = 0.f; mn[j] = INFINITY; mx[j] = -INFINITY; }
  for (int r = r0; r < r1; ++r) {
    bf16x8 v = *(const bf16x8*)(m + (size_t)r * 384 + cw * 8);
#pragma unroll
    for (int j = 0; j < 8; ++j) {
      float x = (float)v[j];
      s[j] += x; s2[j] += x * x;
      mn[j] = fminf(mn[j], x); mx[j] = fmaxf(mx[j], x);
    }
  }
  int d = r1 - r0;
  float cnt1 = (d > 0) ? (float)d : 1.f;
  float inv = 1.f / cnt1;
  bf16x8 vm, vmn, vmx, vsd;
#pragma unroll
  for (int j = 0; j < 8; ++j) {
    float mean = s[j] * inv, msq = s2[j] * inv;
    float var = msq - mean * mean;
    if (var < 0.f) var = 0.f;
    float sd = sqrtf(var + 1e-5f);
    float a = (d == 0) ? 0.f : mn[j];
    float b = (d == 0) ? 0.f : mx[j];
    vm[j] = (bf16)mean; vmn[j] = (bf16)a; vmx[j] = (bf16)b; vsd[j] = (bf16)sd;
  }
  bf16* ag = aggbf2 + (size_t)n * 1536 + cw * 8;
  *(bf16x8*)(ag) = vm;
  *(bf16x8*)(ag + 384) = vmn;
  *(bf16x8*)(ag + 768) = vmx;
  *(bf16x8*)(ag + 1152) = vsd;
}

// Pbuf[ks][n][240] = [hbf|aggbf2](K slice) @ Wct2 ; grid (313,2).
// Prefetch in NAMED registers (no arrays -> no scratch demotion).
#define LOADREGS(c_) do {                                                          \
    int g_ = (c_) * 8 + slb;                                                       \
    const bf16* p_;                                                                \
    if (nA >= NN || g_ >= 202) p_ = zerobuf;                                       \
    else if (g_ < 10)          p_ = hbf + nA * 80 + g_ * 8;                        \
    else                       p_ = aggbf2 + (size_t)nA * 1536 + (g_ - 10) * 8;    \
    pa  = *(const uint4*)p_;                                                       \
    const bf16* wp_ = Wct2 + (size_t)sr * 1664 + (c_) * 64 + slb * 8;              \
    pb0 = *(const uint4*)(wp_ + 0 * 53248);                                        \
    pb1 = *(const uint4*)(wp_ + 1 * 53248);                                        \
    pb2 = *(const uint4*)(wp_ + 2 * 53248);                                        \
    pb3 = *(const uint4*)(wp_ + 3 * 53248);                                        \
    pb4 = *(const uint4*)(wp_ + 4 * 53248);                                        \
    pb5 = *(const uint4*)(wp_ + 5 * 53248);                                        \
    pb6 = *(const uint4*)(wp_ + 6 * 53248);                                        \
    pb7 = *(const uint4*)(wp_ + 7 * 53248);                                        \
  } while (0)

__global__ __launch_bounds__(256) void k_post3(const bf16* __restrict__ hbf,
    const bf16* __restrict__ aggbf2, const bf16* __restrict__ Wct2,
    const bf16* __restrict__ zerobuf, float* __restrict__ Pbuf) {
  __shared__ __align__(16) unsigned char As[4096];
  __shared__ __align__(16) unsigned char Bs[32768];
  const int n0 = blockIdx.x * 32;
  const int ks = blockIdx.y;
  const int cbeg = ks * 13;
  const int tid = threadIdx.x;
  const int lane = tid & 63, wave = tid >> 6;
  const int l15 = lane & 15, l4 = lane >> 4;
  const int sr = tid >> 3, slb = tid & 7;
  const int nA = n0 + sr;
  f32x4 acc[2][4];
  f32x4 zv = {0.f, 0.f, 0.f, 0.f};
#pragma unroll
  for (int i = 0; i < 2; ++i)
#pragma unroll
    for (int j = 0; j < 4; ++j) acc[i][j] = zv;

  uint4 pa, pb0, pb1, pb2, pb3, pb4, pb5, pb6, pb7;
  LOADREGS(cbeg);
  for (int i = 0; i < 13; ++i) {
    *(uint4*)(As + sr * 128 + ((slb ^ (sr & 7)) << 4)) = pa;
    *(uint4*)(Bs + (0 * 32 + sr) * 128 + (slb << 4)) = pb0;
    *(uint4*)(Bs + (1 * 32 + sr) * 128 + (slb << 4)) = pb1;
    *(uint4*)(Bs + (2 * 32 + sr) * 128 + (slb << 4)) = pb2;
    *(uint4*)(Bs + (3 * 32 + sr) * 128 + (slb << 4)) = pb3;
    *(uint4*)(Bs + (4 * 32 + sr) * 128 + (slb << 4)) = pb4;
    *(uint4*)(Bs + (5 * 32 + sr) * 128 + (slb << 4)) = pb5;
    *(uint4*)(Bs + (6 * 32 + sr) * 128 + (slb << 4)) = pb6;
    *(uint4*)(Bs + (7 * 32 + sr) * 128 + (slb << 4)) = pb7;
    __syncthreads();
    if (i < 12) LOADREGS(cbeg + i + 1);   // in flight during ds_read + MFMA
#pragma unroll
    for (int kk = 0; kk < 2; ++kk) {
      int kb = kk * 4 + l4;
      bf16x8 af[2], bv[4];
#pragma unroll
      for (int ii = 0; ii < 2; ++ii) {
        int row = ii * 16 + l15;
        af[ii] = *(const bf16x8*)(As + row * 128 + ((kb ^ (row & 7)) << 4));
      }
#pragma unroll
      for (int j = 0; j < 4; ++j) {
        int col = wave * 64 + j * 16 + l15;
        bv[j] = *(const bf16x8*)(Bs + col * 128 + ((kb ^ (col & 7)) << 4));
      }
#pragma unroll
      for (int ii = 0; ii < 2; ++ii)
#pragma unroll
        for (int j = 0; j < 4; ++j)
          acc[ii][j] = __builtin_amdgcn_mfma_f32_16x16x32_bf16(af[ii], bv[j], acc[ii][j], 0, 0, 0);
    }
    __syncthreads();
  }

#pragma unroll
  for (int ii = 0; ii < 2; ++ii) {
    int rbase = ii * 16 + l4 * 4;
#pragma unroll
    for (int j = 0; j < 4; ++j) {
      int col = wave * 64 + j * 16 + l15;
      if (col < 240) {
#pragma unroll
        for (int q = 0; q < 4; ++q) {
          int n = n0 + rbase + q;
          if (n < NN) Pbuf[((size_t)ks * NN + n) * 240 + col] = acc[ii][j][q];
        }
      }
    }
  }
}

// epilogue: z = (P0a+P0b) + scl*(P1a+P1b) + iscl*(P2a+P2b) + zb; fused BN partial sums.
__global__ __launch_bounds__(256) void k_zep(const float* __restrict__ Pbuf,
    const float* __restrict__ scl, const float* __restrict__ iscl, const float* __restrict__ zb,
    float* __restrict__ z, float* __restrict__ stat_raw) {
  __shared__ float T[64 * 76];
  const int tid = threadIdx.x;
  const int n0 = blockIdx.x * 64;
  for (int idx = tid; idx < 64 * 75; idx += 256) {
    int r = idx / 75, f = idx - r * 75;
    int n = n0 + r;
    float v = 0.f;
    if (n < NN) {
      const float* P0 = Pbuf + (size_t)n * 240;
      const float* P1 = Pbuf + (size_t)(NN + n) * 240;
      v = (P0[f] + P1[f]) + scl[n] * (P0[80 + f] + P1[80 + f])
        + iscl[n] * (P0[160 + f] + P1[160 + f]) + zb[f];
      z[n * 75 + f] = v;
    }
    T[r * 76 + f] = v;
  }
  __syncthreads();
  if (tid < 75) {
    float s = 0.f, s2 = 0.f;
#pragma unroll
    for (int r = 0; r < 64; ++r) {
      float v = T[r * 76 + tid];
      s += v; s2 += v * v;
    }
    atomicAdd(&stat_raw[tid], s);
    atomicAdd(&stat_raw[75 + tid], s2);
  }
}

__global__ __launch_bounds__(256) void k_bnapply(const float* __restrict__ z,
    const float* __restrict__ stat_raw, const float* __restrict__ g, const float* __restrict__ b,
    float* __restrict__ outF, bf16* __restrict__ hbf) {
  int idx = blockIdx.x * 256 + threadIdx.x;
  if (idx >= NN * FD) return;
  int n = idx / FD, f = idx - n * FD;
  float mu = stat_raw[f] * (1.f / NN);
  float var = stat_raw[75 + f] * (1.f / NN) - mu * mu;
  var = fmaxf(var, 0.f);
  float rs = 1.f / sqrtf(var + 1e-5f);
  float v = (z[idx] - mu) * rs * g[f] + b[f];
  v = fmaxf(v, 0.f);
  if (outF) outF[idx] = v;
  hbf[n * 80 + f] = (bf16)v;
}

__global__ __launch_bounds__(256) void k_pool(const float* __restrict__ h, const int* __restrict__ batch,
                                              float* __restrict__ gpool) {
  int idx = blockIdx.x * 256 + threadIdx.x;
  if (idx >= NN * FD) return;
  int n = idx / FD, f = idx - n * FD;
  atomicAdd(&gpool[batch[n] * FD + f], h[idx]);
}

__global__ __launch_bounds__(256) void k_mlp(const float* __restrict__ gpool,
    const float* __restrict__ w1, const float* __restrict__ b1,
    const float* __restrict__ w2, const float* __restrict__ b2,
    const float* __restrict__ w3, const float* __restrict__ b3,
    float* __restrict__ out) {
  __shared__ float G[NGR * FD];
  __shared__ float G1[NGR * 50];
  __shared__ float G2[NGR * 25];
  int tid = threadIdx.x;
  for (int i = tid; i < NGR * FD; i += 256) G[i] = gpool[i];
  __syncthreads();
  for (int i = tid; i < NGR * 50; i += 256) {
    int r = i / 50, c = i - r * 50;
    float a = b1[c];
    for (int k = 0; k < FD; ++k) a += G[r * FD + k] * w1[k * 50 + c];
    G1[i] = fmaxf(a, 0.f);
  }
  __syncthreads();
  for (int i = tid; i < NGR * 25; i += 256) {
    int r = i / 25, c = i - r * 25;
    float a = b2[c];
    for (int k = 0; k < 50; ++k) a += G1[r * 50 + k] * w2[k * 25 + c];
    G2[i] = fmaxf(a, 0.f);
  }
  __syncthreads();
  if (tid < NGR) {
    float a = b3[0];
    for (int k = 0; k < 25; ++k) a += G2[tid * 25 + k] * w3[k];
    out[tid] = a;
  }
}

// ---------------------------------------------------------------- host

extern "C" void kernel_launch(void* const* d_in, const int* in_sizes, int n_in,
                              void* d_out, int out_size, void* d_ws, size_t ws_size,
                              hipStream_t stream) {
  (void)in_sizes; (void)n_in; (void)out_size; (void)ws_size;
  const float* x      = (const float*)d_in[0];
  const int*   eidx   = (const int*)  d_in[1];
  const float* eattr  = (const float*)d_in[2];
  const int*   batch  = (const int*)  d_in[3];
  const float* nw     = (const float*)d_in[4];
  const float* nb     = (const float*)d_in[5];
  const float* ew     = (const float*)d_in[6];
  const float* ebias  = (const float*)d_in[7];
  const float* ee_w   = (const float*)d_in[8];
  const float* ee_b   = (const float*)d_in[9];
  const float* pre_w  = (const float*)d_in[10];
  const float* pre_b  = (const float*)d_in[11];
  const float* post_w = (const float*)d_in[12];
  const float* post_b = (const float*)d_in[13];
  const float* lin_w  = (const float*)d_in[14];
  const float* lin_b  = (const float*)d_in[15];
  const float* bn_g   = (const float*)d_in[16];
  const float* bn_b   = (const float*)d_in[17];
  const float* w1 = (const float*)d_in[18];
  const float* b1 = (const float*)d_in[19];
  const float* w2 = (const float*)d_in[20];
  const float* b2 = (const float*)d_in[21];
  const float* w3 = (const float*)d_in[22];
  const float* b3 = (const float*)d_in[23];

  const int* srcA = eidx;
  const int* dstA = eidx + NE;

  char* base = (char*)d_ws;
  size_t off = 0;
  auto alloc = [&](size_t bytes) -> char* {
    char* p = base + off;
    off = (off + bytes + 255) & ~(size_t)255;
    return p;
  };
  bf16*  hbf    = (bf16*) alloc((size_t)NN * 80 * 2);
  bf16*  eabf   = (bf16*) alloc((size_t)NE * 56 * 2);
  bf16*  mbf    = (bf16*) alloc((size_t)NE * 384 * 2);
  bf16*  aggbf2 = (bf16*) alloc((size_t)NN * 1536 * 2);
  float* z      = (float*)alloc((size_t)NN * FD * 4);
  float* Pbuf   = (float*)alloc((size_t)2 * NN * 240 * 4);
  bf16*  WctA   = (bf16*) alloc((size_t)NLAY * 384 * 256 * 2);
  float* bcA    = (float*)alloc((size_t)NLAY * 384 * 4);
  bf16*  Wct2A  = (bf16*) alloc((size_t)NLAY * 256 * 1664 * 2);
  float* zbA    = (float*)alloc((size_t)NLAY * 80 * 4);
  float* PL     = (float*)alloc((size_t)5 * 975 * 80 * 4);
  float* scl    = (float*)alloc(NN * 4);
  float* iscl   = (float*)alloc(NN * 4);
  int*   deg    = (int*)alloc(NN * 4);
  int*   rowptr = (int*)alloc((NN + 1) * 4);
  int*   cursor = (int*)alloc(NN * 4);
  int*   eids   = (int*)alloc(NE * 4);
  float* stat_raw = (float*)alloc(2 * FD * 4);
  float* gpool  = (float*)alloc(NGR * FD * 4);
  bf16*  zerobuf = (bf16*)alloc(256);

  static const int DEG_TAB[71] = {1, 72, 201, 816, 1790, 3756, 6923, 12768, 20286, 31710,
    51623, 82296, 124280, 177576, 251115, 326064, 395760, 456840, 506179, 516200, 507003,
    493746, 489256, 453936, 420025, 411320, 427761, 420700, 420500, 426780, 414284, 407008,
    394053, 360910, 322245, 313704, 282902, 270940, 237783, 209000, 193766, 177870, 162110,
    144848, 121230, 112700, 93483, 88512, 72275, 80700, 68799, 56784, 42665, 30996, 25630,
    12936, 9804, 8584, 5251, 3480, 3111, 2728, 1890, 1472, 1235, 330, 201, 68, 69, 0, 71};
  double num = 0.0, den = 0.0;
  for (int i = 0; i < 71; ++i) { num += log((double)i + 1.0) * DEG_TAB[i]; den += DEG_TAB[i]; }
  float inv_avg_log = (float)(den / num);

  hipMemsetAsync(deg, 0, NN * 4, stream);
  hipMemsetAsync(cursor, 0, NN * 4, stream);
  hipMemsetAsync(gpool, 0, NGR * FD * 4, stream);
  hipMemsetAsync(zerobuf, 0, 256, stream);

  // graph prep
  k_node_emb<<<(NN * FD + 255) / 256, 256, 0, stream>>>(x, nw, nb, hbf);
  k_edge_emb<<<(NE * 50 + 255) / 256, 256, 0, stream>>>(eattr, ew, ebias, eabf);
  k_count<<<(NE + 255) / 256, 256, 0, stream>>>(dstA, deg);
  k_scan<<<1, 1024, 0, stream>>>(deg, rowptr);
  k_scl<<<(NN + 255) / 256, 256, 0, stream>>>(deg, scl, iscl, inv_avg_log);
  k_scatter<<<(NE + 255) / 256, 256, 0, stream>>>(dstA, rowptr, cursor, eids);

  // weight prep, all layers up front
  for (int l = 0; l < NLAY; ++l) {
    k_combine<<<384, 256, 0, stream>>>(
        pre_w + (size_t)l * NT * 225 * FD, pre_b + (size_t)l * NT * FD,
        ee_w + (size_t)l * 50 * FD, ee_b + (size_t)l * FD,
        WctA + (size_t)l * 384 * 256, bcA + (size_t)l * 384);
    k_PL<<<(5 * 975 * 80 + 255) / 256, 256, 0, stream>>>(
        post_w + (size_t)l * NT * 975 * FOUT, lin_w + (size_t)l * FD * FD, PL);
    k_combine2b<<<(256 * 1664 + 255) / 256, 256, 0, stream>>>(PL, Wct2A + (size_t)l * 256 * 1664);
    k_zbias<<<1, 128, 0, stream>>>(post_b + (size_t)l * NT * FOUT,
        lin_w + (size_t)l * FD * FD, lin_b + (size_t)l * FD, zbA + (size_t)l * 80);
  }

  float* outp = (float*)d_out;
  for (int l = 0; l < NLAY; ++l) {
    dim3 gpre((NE + 127) / 128, 3);
    k_pre_mfma<<<gpre, 256, 0, stream>>>(hbf, eabf, eids, srcA, dstA,
        WctA + (size_t)l * 384 * 256, bcA + (size_t)l * 384, zerobuf, mbf);
    k_agg2<<<(NN + 7) / 8, 384, 0, stream>>>(mbf, rowptr, aggbf2);
    dim3 gpost((NN + 31) / 32, 2);
    k_post3<<<gpost, 256, 0, stream>>>(hbf, aggbf2, Wct2A + (size_t)l * 256 * 1664, zerobuf, Pbuf);
    hipMemsetAsync(stat_raw, 0, 2 * FD * 4, stream);
    k_zep<<<(NN + 63) / 64, 256, 0, stream>>>(Pbuf, scl, iscl, zbA + (size_t)l * 80, z, stat_raw);
    float* wdst = (l == NLAY - 1) ? (outp + NGR) : nullptr;
    k_bnapply<<<(NN * FD + 255) / 256, 256, 0, stream>>>(z, stat_raw, bn_g + (size_t)l * FD,
        bn_b + (size_t)l * FD, wdst, hbf);
  }

  k_pool<<<(NN * FD + 255) / 256, 256, 0, stream>>>(outp + NGR, batch, gpool);
  k_mlp<<<1, 256, 0, stream>>>(gpool, w1, b1, w2, b2, w3, b3, outp);
}